// Round 5
// baseline (573.672 us; speedup 1.0000x reference)
//
#include <hip/hip_runtime.h>

typedef __bf16 bf16;
typedef __attribute__((ext_vector_type(8))) __bf16 bf16x8;
typedef __attribute__((ext_vector_type(4))) __bf16 bf16x4;
typedef __attribute__((ext_vector_type(4))) float  f32x4;

// ---------- helpers ----------
__device__ __forceinline__ f32x4 mfma16(bf16x8 a, bf16x8 b, f32x4 c) {
    return __builtin_amdgcn_mfma_f32_16x16x32_bf16(a, b, c, 0, 0, 0);
}

__device__ __forceinline__ void stash8(bf16* dst, float4 a, float4 b) {
    bf16x8 v;
    v[0] = (bf16)a.x; v[1] = (bf16)a.y; v[2] = (bf16)a.z; v[3] = (bf16)a.w;
    v[4] = (bf16)b.x; v[5] = (bf16)b.y; v[6] = (bf16)b.z; v[7] = (bf16)b.w;
    *reinterpret_cast<bf16x8*>(dst) = v;
}

// load 8 consecutive f32 -> bf16x8 (for direct A-fragment construction)
__device__ __forceinline__ bf16x8 ldf8(const float* p) {
    float4 a = *reinterpret_cast<const float4*>(p);
    float4 b = *reinterpret_cast<const float4*>(p + 4);
    bf16x8 v;
    v[0] = (bf16)a.x; v[1] = (bf16)a.y; v[2] = (bf16)a.z; v[3] = (bf16)a.w;
    v[4] = (bf16)b.x; v[5] = (bf16)b.y; v[6] = (bf16)b.z; v[7] = (bf16)b.w;
    return v;
}

// B-fragment from PRE-SWIZZLED weights: 64 lanes read one contiguous 1KB block.
__device__ __forceinline__ bf16x8 wfrag(const bf16* __restrict__ W, int s, int n, int lane) {
    return *reinterpret_cast<const bf16x8*>(W + (((s * 4 + n) * 64 + lane) * 8));
}

// 2-M-tile (32 rows) x 4-N-tile (64 cols) MFMA matmul; A from LDS (pitch P),
// B from swizzled weights, KS k-steps of 32.
template<int P, int KS>
__device__ __forceinline__ void mm2s(const bf16* __restrict__ src, int kofs,
                                     const bf16* __restrict__ W,
                                     int lane, f32x4 (&acc)[2][4]) {
    const int c16 = lane & 15, g = lane >> 4;
#pragma unroll
    for (int m = 0; m < 2; ++m)
#pragma unroll
        for (int n = 0; n < 4; ++n) acc[m][n] = 0.0f;
#pragma unroll
    for (int s = 0; s < KS; ++s) {
        bf16x8 aA = *reinterpret_cast<const bf16x8*>(src + c16 * P + kofs + s * 32 + g * 8);
        bf16x8 aB = *reinterpret_cast<const bf16x8*>(src + (16 + c16) * P + kofs + s * 32 + g * 8);
#pragma unroll
        for (int n = 0; n < 4; ++n) {
            bf16x8 bb = wfrag(W, s, n, lane);
            acc[0][n] = mfma16(aA, bb, acc[0][n]);
            acc[1][n] = mfma16(aB, bb, acc[1][n]);
        }
    }
}

// single-M-tile (16 rows) variant for the node kernel
template<int P, int KS>
__device__ __forceinline__ void mm1s(const bf16* __restrict__ src, int kofs,
                                     const bf16* __restrict__ W,
                                     int lane, f32x4 (&acc)[4]) {
    const int c16 = lane & 15, g = lane >> 4;
#pragma unroll
    for (int n = 0; n < 4; ++n) acc[n] = 0.0f;
#pragma unroll
    for (int s = 0; s < KS; ++s) {
        bf16x8 a = *reinterpret_cast<const bf16x8*>(src + c16 * P + kofs + s * 32 + g * 8);
#pragma unroll
        for (int n = 0; n < 4; ++n) {
            bf16x8 bb = wfrag(W, s, n, lane);
            acc[n] = mfma16(a, bb, acc[n]);
        }
    }
}

__device__ __forceinline__ void storeh2(bf16* hbw, const f32x4 (&acc)[2][4],
                                        const float* __restrict__ bias, int c16, int g) {
#pragma unroll
    for (int n = 0; n < 4; ++n) {
        float bb = bias[n * 16 + c16];
#pragma unroll
        for (int m = 0; m < 2; ++m)
#pragma unroll
            for (int r = 0; r < 4; ++r)
                hbw[(m * 16 + g * 4 + r) * 72 + n * 16 + c16] = (bf16)fmaxf(acc[m][n][r] + bb, 0.0f);
    }
}

__device__ __forceinline__ void storeh1(bf16* hbw, const f32x4 (&acc)[4],
                                        const float* __restrict__ bias, int c16, int g) {
#pragma unroll
    for (int n = 0; n < 4; ++n) {
        float bb = bias[n * 16 + c16];
#pragma unroll
        for (int r = 0; r < 4; ++r)
            hbw[(g * 4 + r) * 72 + n * 16 + c16] = (bf16)fmaxf(acc[n][r] + bb, 0.0f);
    }
}

// ---------- prep: f32 -> bf16 weight conversion + fragment-order swizzle ----------
struct PrepArgs {
    const float* src[10];
    bf16* dst[10];
    int ofs[11];
    int ldk[10];
};

__global__ void prep_kernel(PrepArgs a, int totalFrag) {
    int t = blockIdx.x * 256 + threadIdx.x;
    if (t >= totalFrag) return;
    int eb = t * 8;
    int k = 0;
    while (k < 9 && eb >= a.ofs[k + 1]) ++k;
    int f = (eb - a.ofs[k]) >> 3;
    int lane = f & 63, n = (f >> 6) & 3, s = f >> 8;
    int c16 = lane & 15, g = lane >> 4;
    const float* sp = a.src[k] + (n * 16 + c16) * a.ldk[k] + s * 32 + g * 8;
    float4 v0 = *reinterpret_cast<const float4*>(sp);
    float4 v1 = *reinterpret_cast<const float4*>(sp + 4);
    stash8(a.dst[k] + (size_t)f * 8, v0, v1);
}

// ---------- E1: edge MLP + QKV + scores + degree count ----------
// 4 waves/block, 32 edges/wave. x_dst/x_src/edge_attr all loaded directly as
// A-fragments (no input LDS staging). Single LDS buffer for inter-layer
// transposes. Dense full-line stores for eout and V.
__global__ __launch_bounds__(256, 5) void e1_kernel(
    const float* __restrict__ x, const int* __restrict__ ei, const float* __restrict__ ea,
    const bf16* __restrict__ W0, const bf16* __restrict__ W1, const bf16* __restrict__ W2,
    const bf16* __restrict__ Wq, const bf16* __restrict__ Wk, const bf16* __restrict__ Wv,
    const float* __restrict__ b0, const float* __restrict__ b1, const float* __restrict__ b2,
    const float* __restrict__ egm, const float* __restrict__ ebe,
    float* __restrict__ scoresOut, int* __restrict__ deg,
    bf16* __restrict__ Vout, float* __restrict__ eout, int E)
{
    __shared__ bf16 hbl[4][32][72];   // inter-layer transpose buffer, pitch 72
    const int w = threadIdx.x >> 6;
    const int lane = threadIdx.x & 63;
    const int ebase = blockIdx.x * 128 + w * 32;
    bf16* hbw = &hbl[w][0][0];
    const int g = lane >> 4, c16 = lane & 15;

    // ---- degree count for CSR
    if (threadIdx.x < 128) {
        int e = blockIdx.x * 128 + threadIdx.x;
        atomicAdd(&deg[ei[E + e]], 1);
    }

    // ---- direct A-fragment loads of x_dst / x_src / edge_attr (issued up-front)
    const int eA0 = ebase + c16, eA1 = ebase + 16 + c16;
    const int dn0 = ei[E + eA0], dn1 = ei[E + eA1];
    const int sn0 = ei[eA0],     sn1 = ei[eA1];
    const float* xd0 = x + (size_t)dn0 * 64;
    const float* xd1 = x + (size_t)dn1 * 64;
    const float* xs0 = x + (size_t)sn0 * 64;
    const float* xs1 = x + (size_t)sn1 * 64;
    const float* ea0 = ea + (size_t)eA0 * 64;
    const float* ea1 = ea + (size_t)eA1 * 64;
    bf16x8 fxd[2][2], fxs[2][2], fxe[2][2];
#pragma unroll
    for (int s = 0; s < 2; ++s) {
        fxd[0][s] = ldf8(xd0 + s * 32 + g * 8);
        fxd[1][s] = ldf8(xd1 + s * 32 + g * 8);
        fxs[0][s] = ldf8(xs0 + s * 32 + g * 8);
        fxs[1][s] = ldf8(xs1 + s * 32 + g * 8);
        fxe[0][s] = ldf8(ea0 + s * 32 + g * 8);
        fxe[1][s] = ldf8(ea1 + s * 32 + g * 8);
    }

    // ---- Q (x_dst), K (x_src) + per-head scores (transient registers)
    {
        f32x4 aq[2][4], ak[2][4];
#pragma unroll
        for (int m = 0; m < 2; ++m)
#pragma unroll
            for (int n = 0; n < 4; ++n) { aq[m][n] = 0.0f; ak[m][n] = 0.0f; }
#pragma unroll
        for (int s = 0; s < 2; ++s)
#pragma unroll
            for (int n = 0; n < 4; ++n) {
                bf16x8 bq = wfrag(Wq, s, n, lane);
                bf16x8 bk = wfrag(Wk, s, n, lane);
                aq[0][n] = mfma16(fxd[0][s], bq, aq[0][n]);
                aq[1][n] = mfma16(fxd[1][s], bq, aq[1][n]);
                ak[0][n] = mfma16(fxs[0][s], bk, ak[0][n]);
                ak[1][n] = mfma16(fxs[1][s], bk, ak[1][n]);
            }
#pragma unroll
        for (int n = 0; n < 4; ++n) {
#pragma unroll
            for (int m = 0; m < 2; ++m) {
                float pr[4];
#pragma unroll
                for (int r = 0; r < 4; ++r) pr[r] = aq[m][n][r] * ak[m][n][r];
#pragma unroll
                for (int ms = 1; ms < 16; ms <<= 1)
#pragma unroll
                    for (int r = 0; r < 4; ++r) pr[r] += __shfl_xor(pr[r], ms);
                if (c16 == n) {
#pragma unroll
                    for (int r = 0; r < 4; ++r) {
                        int e2 = ebase + m * 16 + g * 4 + r;
                        scoresOut[(size_t)e2 * 4 + n] = pr[r] * 0.25f;  // / sqrt(16)
                    }
                }
            }
        }
    }

    // ---- L0: W0 * [xd | xs | ea]  (K = 192; swizzled W0, s6 = 0..5)
    f32x4 acc[2][4], acc2[2][4];
#pragma unroll
    for (int m = 0; m < 2; ++m)
#pragma unroll
        for (int n = 0; n < 4; ++n) acc[m][n] = 0.0f;
#pragma unroll
    for (int s = 0; s < 2; ++s)
#pragma unroll
        for (int n = 0; n < 4; ++n) {
            bf16x8 bd = wfrag(W0, s, n, lane);
            acc[0][n] = mfma16(fxd[0][s], bd, acc[0][n]);
            acc[1][n] = mfma16(fxd[1][s], bd, acc[1][n]);
            bf16x8 bs = wfrag(W0, s + 2, n, lane);
            acc[0][n] = mfma16(fxs[0][s], bs, acc[0][n]);
            acc[1][n] = mfma16(fxs[1][s], bs, acc[1][n]);
            bf16x8 be = wfrag(W0, s + 4, n, lane);
            acc[0][n] = mfma16(fxe[0][s], be, acc[0][n]);
            acc[1][n] = mfma16(fxe[1][s], be, acc[1][n]);
        }

    // ---- relu -> L1 -> relu -> L2 + b2
    storeh2(hbw, acc, b0, c16, g);
    mm2s<72, 2>(hbw, 0, W1, lane, acc);
    storeh2(hbw, acc, b1, c16, g);
    mm2s<72, 2>(hbw, 0, W2, lane, acc2);
#pragma unroll
    for (int n = 0; n < 4; ++n) {
        float bb = b2[n * 16 + c16];
#pragma unroll
        for (int m = 0; m < 2; ++m)
#pragma unroll
            for (int r = 0; r < 4; ++r) acc2[m][n][r] += bb;
    }

    // ---- LayerNorm over 64 channels per edge row (wave-local shuffles)
    float mu[2][4], rs[2][4];
#pragma unroll
    for (int m = 0; m < 2; ++m)
#pragma unroll
        for (int r = 0; r < 4; ++r) {
            float s1 = acc2[m][0][r] + acc2[m][1][r] + acc2[m][2][r] + acc2[m][3][r];
            for (int ms = 1; ms < 16; ms <<= 1) s1 += __shfl_xor(s1, ms);
            float mm = s1 * (1.0f / 64.0f);
            float d0 = acc2[m][0][r] - mm, d1 = acc2[m][1][r] - mm;
            float d2 = acc2[m][2][r] - mm, d3 = acc2[m][3][r] - mm;
            float sq = d0 * d0 + d1 * d1 + d2 * d2 + d3 * d3;
            for (int ms = 1; ms < 16; ms <<= 1) sq += __shfl_xor(sq, ms);
            mu[m][r] = mm;
            rs[m][r] = rsqrtf(sq * (1.0f / 64.0f) + 1e-5f);
        }

    // ---- e_new -> hbl (A-layout, bf16)
#pragma unroll
    for (int n = 0; n < 4; ++n) {
        float gg = egm[n * 16 + c16], bb = ebe[n * 16 + c16];
#pragma unroll
        for (int m = 0; m < 2; ++m)
#pragma unroll
            for (int r = 0; r < 4; ++r) {
                int rowi = m * 16 + g * 4 + r;
                float v = (acc2[m][n][r] - mu[m][r]) * rs[m][r] * gg + bb;
                hbw[rowi * 72 + n * 16 + c16] = (bf16)v;
            }
    }

    // ---- eout = edge_attr(f32, re-read L2-hot) + e_new; DENSE 256B/row stores
#pragma unroll
    for (int i = 0; i < 8; ++i) {
        int row = i * 4 + (lane >> 4);     // 0..31
        int colf = (lane & 15) * 4;        // 0..60
        const bf16* hp = hbw + row * 72 + colf;
        const float* ap = ea + (size_t)(ebase + row) * 64 + colf;
        float4 av = *reinterpret_cast<const float4*>(ap);
        float4 o;
        o.x = av.x + (float)hp[0];
        o.y = av.y + (float)hp[1];
        o.z = av.z + (float)hp[2];
        o.w = av.w + (float)hp[3];
        *reinterpret_cast<float4*>(eout + (size_t)(ebase + row) * 64 + colf) = o;
    }

    // ---- V = e_new @ wv.T ; stage C-layout to LDS, DENSE 1KB/instr store
    mm2s<72, 2>(hbw, 0, Wv, lane, acc);
#pragma unroll
    for (int n = 0; n < 4; ++n)
#pragma unroll
        for (int m = 0; m < 2; ++m)
#pragma unroll
            for (int r = 0; r < 4; ++r)
                hbw[(m * 16 + g * 4 + r) * 72 + n * 16 + c16] = (bf16)acc[m][n][r];
#pragma unroll
    for (int k = 0; k < 4; ++k) {
        int row = k * 8 + (lane >> 3);     // 0..31
        int col = (lane & 7) * 8;          // 0..56
        bf16x8 v = *reinterpret_cast<const bf16x8*>(hbw + row * 72 + col);
        *reinterpret_cast<bf16x8*>(Vout + (size_t)(ebase + row) * 64 + col) = v;
    }
}

// ---------- CSR scan: block-local exclusive scan + hierarchical block sums ----------
__global__ __launch_bounds__(256) void scan1_kernel(const int* __restrict__ deg, int* __restrict__ ofs,
                                                    int* __restrict__ bsum, int N) {
    __shared__ int ws4[4];
    const int t = threadIdx.x, lane = t & 63, w = t >> 6;
    const int i = blockIdx.x * 256 + t;
    const int v = (i < N) ? deg[i] : 0;
    int inc = v;
#pragma unroll
    for (int o = 1; o < 64; o <<= 1) { int u = __shfl_up(inc, o); if (lane >= o) inc += u; }
    if (lane == 63) ws4[w] = inc;
    __syncthreads();
    int add = 0;
    for (int k = 0; k < w; ++k) add += ws4[k];
    if (i < N) ofs[i] = inc - v + add;
    if (t == 255) bsum[blockIdx.x] = inc + add;  // block total
}

__global__ __launch_bounds__(256) void scan2_kernel(int* __restrict__ bsum, int nb) {
    __shared__ int ws4[4];
    const int t = threadIdx.x, lane = t & 63, w = t >> 6;
    const int v = (t < nb) ? bsum[t] : 0;
    int inc = v;
#pragma unroll
    for (int o = 1; o < 64; o <<= 1) { int u = __shfl_up(inc, o); if (lane >= o) inc += u; }
    if (lane == 63) ws4[w] = inc;
    __syncthreads();
    int add = 0;
    for (int k = 0; k < w; ++k) add += ws4[k];
    if (t < nb) bsum[t] = inc - v + add;
}

__global__ __launch_bounds__(256) void scan3_kernel(int* __restrict__ ofs, const int* __restrict__ bsum, int N) {
    const int i = blockIdx.x * 256 + threadIdx.x;
    if (i < N) ofs[i] += bsum[blockIdx.x];
}

// ---------- CSR fill ----------
__global__ __launch_bounds__(256) void fill_kernel(const int* __restrict__ ei, const int* __restrict__ ofs,
                                                   int* __restrict__ cur, int* __restrict__ eidT, int E) {
    const int e = blockIdx.x * 256 + threadIdx.x;
    if (e >= E) return;
    const int d = ei[E + e];
    const int slot = atomicAdd(&cur[d], 1);
    eidT[ofs[d] + slot] = e;
}

// ---------- gather: per-node online softmax + weighted V sum (one wave per node) ----------
__global__ __launch_bounds__(256) void gather_kernel(
    const int* __restrict__ deg, const int* __restrict__ ofs, const int* __restrict__ eidT,
    const float* __restrict__ scores, const bf16* __restrict__ V,
    bf16* __restrict__ msg, int N)
{
    const int w = threadIdx.x >> 6, lane = threadIdx.x & 63;
    const int n = blockIdx.x * 4 + w;
    if (n >= N) return;
    const int cnt = deg[n];
    const int* lst = eidT + ofs[n];
    const int h = lane >> 4;
    float m = -3.4e38f, s = 0.f, acc = 0.f;

    // preload up to 128 edge ids into registers (one per lane, two banks)
    int eA = (lane < cnt) ? lst[lane] : 0;
    int eB = (64 + lane < cnt) ? lst[64 + lane] : 0;
    const int nr = min(cnt, 128);
    if (nr > 0) {
        int e = __shfl(eA, 0);
        float sc = scores[(size_t)e * 4 + h];
        float v  = (float)V[(size_t)e * 64 + lane];
        for (int i = 1; i <= nr; ++i) {
            float sc2 = 0.f, v2 = 0.f;
            if (i < nr) {  // prefetch next edge's data while updating with current
                int e2 = __shfl((i < 64) ? eA : eB, i & 63);
                sc2 = scores[(size_t)e2 * 4 + h];
                v2  = (float)V[(size_t)e2 * 64 + lane];
            }
            float mn = fmaxf(m, sc);
            float c  = __expf(m - mn);
            float ex = __expf(sc - mn);
            s = s * c + ex;
            acc = acc * c + ex * v;
            m = mn;
            sc = sc2; v = v2;
        }
    }
    for (int i = 128; i < cnt; ++i) {  // overflow path (deg > 128), statistically never hit
        int e = lst[i];
        float sc = scores[(size_t)e * 4 + h];
        float v  = (float)V[(size_t)e * 64 + lane];
        float mn = fmaxf(m, sc);
        float c  = __expf(m - mn);
        float ex = __expf(sc - mn);
        s = s * c + ex;
        acc = acc * c + ex * v;
        m = mn;
    }
    msg[(size_t)n * 64 + lane] = (bf16)(acc / (s + 1e-12f));
}

// ---------- N: node MLP ----------
__global__ __launch_bounds__(256, 2) void n_kernel(
    const float* __restrict__ x, const bf16* __restrict__ msg,
    const bf16* __restrict__ Wo, const bf16* __restrict__ W0, const bf16* __restrict__ W1,
    const bf16* __restrict__ W2,
    const float* __restrict__ b0, const float* __restrict__ b1, const float* __restrict__ b2,
    const float* __restrict__ ngm, const float* __restrict__ nbe,
    float* __restrict__ xout, int N)
{
    __shared__ bf16 cat[4][16][136];  // [x | msg@wo.T], pitch 136
    __shared__ bf16 hbl[4][16][72];
    const int w = threadIdx.x >> 6, lane = threadIdx.x & 63;
    const int nbase = blockIdx.x * 64 + w * 16;
    bf16* catw = &cat[w][0][0];
    bf16* hbw  = &hbl[w][0][0];

    {   // stage x (bf16) into cat[0..63]; msg (bf16) into hbw
        const int r = lane >> 2, q = lane & 3;  // 4 lanes/row, 16 cols each
        const int nd = min(nbase + r, N - 1);
        const float4* xp = reinterpret_cast<const float4*>(x) + (size_t)nd * 16 + q * 4;
        stash8(catw + r * 136 + q * 16,     xp[0], xp[1]);
        stash8(catw + r * 136 + q * 16 + 8, xp[2], xp[3]);
        const bf16* mp = msg + (size_t)nd * 64 + q * 16;
        *reinterpret_cast<bf16x8*>(hbw + r * 72 + q * 16)     = *reinterpret_cast<const bf16x8*>(mp);
        *reinterpret_cast<bf16x8*>(hbw + r * 72 + q * 16 + 8) = *reinterpret_cast<const bf16x8*>(mp + 8);
    }
    const int g = lane >> 4, c16 = lane & 15;
    f32x4 acc[4];

    // msgO = msg @ wo.T  -> cat[64..127]
    mm1s<72, 2>(hbw, 0, Wo, lane, acc);
#pragma unroll
    for (int n = 0; n < 4; ++n)
#pragma unroll
        for (int r = 0; r < 4; ++r)
            catw[(g * 4 + r) * 136 + 64 + n * 16 + c16] = (bf16)acc[n][r];

    // node MLP
    mm1s<136, 4>(catw, 0, W0, lane, acc);
    storeh1(hbw, acc, b0, c16, g);
    mm1s<72, 2>(hbw, 0, W1, lane, acc);
    storeh1(hbw, acc, b1, c16, g);
    mm1s<72, 2>(hbw, 0, W2, lane, acc);
#pragma unroll
    for (int n = 0; n < 4; ++n) {
        float bb = b2[n * 16 + c16];
#pragma unroll
        for (int r = 0; r < 4; ++r) acc[n][r] += bb;
    }

    // LayerNorm + residual
    float mu[4], rs[4];
#pragma unroll
    for (int r = 0; r < 4; ++r) {
        float s1 = acc[0][r] + acc[1][r] + acc[2][r] + acc[3][r];
        for (int ms = 1; ms < 16; ms <<= 1) s1 += __shfl_xor(s1, ms);
        float mm = s1 * (1.0f / 64.0f);
        float d0 = acc[0][r] - mm, d1 = acc[1][r] - mm, d2 = acc[2][r] - mm, d3 = acc[3][r] - mm;
        float sq = d0 * d0 + d1 * d1 + d2 * d2 + d3 * d3;
        for (int ms = 1; ms < 16; ms <<= 1) sq += __shfl_xor(sq, ms);
        mu[r] = mm;
        rs[r] = rsqrtf(sq * (1.0f / 64.0f) + 1e-5f);
    }
#pragma unroll
    for (int n = 0; n < 4; ++n) {
        float gg = ngm[n * 16 + c16], bb = nbe[n * 16 + c16];
#pragma unroll
        for (int r = 0; r < 4; ++r) {
            int rowi = g * 4 + r;
            int node = nbase + rowi;
            float v = (acc[n][r] - mu[r]) * rs[r] * gg + bb;
            if (node < N) {
                size_t o = (size_t)node * 64 + n * 16 + c16;
                xout[o] = x[o] + v;
            }
        }
    }
}

// ---------- launcher ----------
extern "C" void kernel_launch(void* const* d_in, const int* in_sizes, int n_in,
                              void* d_out, int out_size, void* d_ws, size_t ws_size,
                              hipStream_t stream)
{
    const float* x   = (const float*)d_in[0];
    const int*   ei  = (const int*)d_in[1];
    const float* ea  = (const float*)d_in[2];
    const float* ew0 = (const float*)d_in[3];
    const float* eb0 = (const float*)d_in[4];
    const float* ew1 = (const float*)d_in[5];
    const float* eb1 = (const float*)d_in[6];
    const float* ew2 = (const float*)d_in[7];
    const float* eb2 = (const float*)d_in[8];
    const float* egm = (const float*)d_in[9];
    const float* ebe = (const float*)d_in[10];
    const float* nw0 = (const float*)d_in[11];
    const float* nb0 = (const float*)d_in[12];
    const float* nw1 = (const float*)d_in[13];
    const float* nb1 = (const float*)d_in[14];
    const float* nw2 = (const float*)d_in[15];
    const float* nb2 = (const float*)d_in[16];
    const float* ngm = (const float*)d_in[17];
    const float* nbe = (const float*)d_in[18];
    const float* wq  = (const float*)d_in[19];
    const float* wk  = (const float*)d_in[20];
    const float* wv  = (const float*)d_in[21];
    const float* wo  = (const float*)d_in[22];

    const int Nn = in_sizes[0] / 64;
    const int Ee = in_sizes[1] / 2;

    char* p = (char*)d_ws;
    auto carve = [&](size_t bytes) {
        char* r = p;
        p += (bytes + 255) & ~(size_t)255;
        return r;
    };
    bf16* W0e = (bf16*)carve(64 * 192 * 2);
    bf16* W1e = (bf16*)carve(64 * 64 * 2);
    bf16* W2e = (bf16*)carve(64 * 64 * 2);
    bf16* Wqb = (bf16*)carve(64 * 64 * 2);
    bf16* Wkb = (bf16*)carve(64 * 64 * 2);
    bf16* Wvb = (bf16*)carve(64 * 64 * 2);
    bf16* Wob = (bf16*)carve(64 * 64 * 2);
    bf16* W0n = (bf16*)carve(64 * 128 * 2);
    bf16* W1n = (bf16*)carve(64 * 64 * 2);
    bf16* W2n = (bf16*)carve(64 * 64 * 2);
    float* scores = (float*)carve((size_t)Ee * 4 * 4);
    bf16*  V      = (bf16*)carve((size_t)Ee * 64 * 2);
    bf16*  msg    = (bf16*)carve((size_t)Nn * 64 * 2);
    int*   deg    = (int*)carve((size_t)Nn * 4);
    int*   ofs    = (int*)carve((size_t)Nn * 4);
    int*   cur    = (int*)carve((size_t)Nn * 4);
    int*   eidT   = (int*)carve((size_t)Ee * 4);
    int*   bsum   = (int*)carve(((size_t)Nn / 256 + 2) * 4);

    hipMemsetAsync(deg, 0, (size_t)Nn * 4, stream);
    hipMemsetAsync(cur, 0, (size_t)Nn * 4, stream);

    PrepArgs pa;
    const float* srcs[10] = {ew0, ew1, ew2, wq, wk, wv, wo, nw0, nw1, nw2};
    bf16* dsts[10]        = {W0e, W1e, W2e, Wqb, Wkb, Wvb, Wob, W0n, W1n, W2n};
    const int sizes[10]   = {12288, 4096, 4096, 4096, 4096, 4096, 4096, 8192, 4096, 4096};
    const int ldks[10]    = {192, 64, 64, 64, 64, 64, 64, 128, 64, 64};
    int acc_ofs = 0;
    for (int i = 0; i < 10; ++i) {
        pa.src[i] = srcs[i];
        pa.dst[i] = dsts[i];
        pa.ofs[i] = acc_ofs;
        pa.ldk[i] = ldks[i];
        acc_ofs += sizes[i];
    }
    pa.ofs[10] = acc_ofs;
    const int totalFrag = acc_ofs / 8;
    prep_kernel<<<(totalFrag + 255) / 256, 256, 0, stream>>>(pa, totalFrag);

    float* xout = (float*)d_out;
    float* eout = (float*)d_out + (size_t)Nn * 64;

    // edge MLP + scores + V + degree histogram
    e1_kernel<<<Ee / 128, 256, 0, stream>>>(x, ei, ea, W0e, W1e, W2e, Wqb, Wkb, Wvb,
                                            eb0, eb1, eb2, egm, ebe,
                                            scores, deg, V, eout, Ee);

    // CSR offsets (exclusive scan of deg)
    const int nb = (Nn + 255) / 256;
    scan1_kernel<<<nb, 256, 0, stream>>>(deg, ofs, bsum, Nn);
    scan2_kernel<<<1, 256, 0, stream>>>(bsum, nb);
    scan3_kernel<<<nb, 256, 0, stream>>>(ofs, bsum, Nn);
    fill_kernel<<<(Ee + 255) / 256, 256, 0, stream>>>(ei, ofs, cur, eidT, Ee);

    // per-node softmax-weighted gather
    gather_kernel<<<(Nn + 3) / 4, 256, 0, stream>>>(deg, ofs, eidT, scores, V, msg, Nn);

    // node MLP
    n_kernel<<<(Nn + 63) / 64, 256, 0, stream>>>(x, msg, Wob, W0n, W1n, W2n,
                                                 nb0, nb1, nb2, ngm, nbe, xout, Nn);
}

// Round 6
// 478.659 us; speedup vs baseline: 1.1985x; 1.1985x over previous
//
#include <hip/hip_runtime.h>

typedef __bf16 bf16;
typedef __attribute__((ext_vector_type(8))) __bf16 bf16x8;
typedef __attribute__((ext_vector_type(4))) __bf16 bf16x4;
typedef __attribute__((ext_vector_type(4))) float  f32x4;

// ---------- helpers ----------
__device__ __forceinline__ f32x4 mfma16(bf16x8 a, bf16x8 b, f32x4 c) {
    return __builtin_amdgcn_mfma_f32_16x16x32_bf16(a, b, c, 0, 0, 0);
}

__device__ __forceinline__ void stash8(bf16* dst, float4 a, float4 b) {
    bf16x8 v;
    v[0] = (bf16)a.x; v[1] = (bf16)a.y; v[2] = (bf16)a.z; v[3] = (bf16)a.w;
    v[4] = (bf16)b.x; v[5] = (bf16)b.y; v[6] = (bf16)b.z; v[7] = (bf16)b.w;
    *reinterpret_cast<bf16x8*>(dst) = v;
}

// B-fragment from PRE-SWIZZLED weights: 64 lanes read one contiguous 1KB block.
__device__ __forceinline__ bf16x8 wfrag(const bf16* __restrict__ W, int s, int n, int lane) {
    return *reinterpret_cast<const bf16x8*>(W + (((s * 4 + n) * 64 + lane) * 8));
}

// 2-M-tile x 4-N-tile MFMA matmul; A from LDS (pitch P), B swizzled, KS k-steps.
template<int P, int KS>
__device__ __forceinline__ void mm2s(const bf16* __restrict__ src, int kofs,
                                     const bf16* __restrict__ W,
                                     int lane, f32x4 (&acc)[2][4]) {
    const int c16 = lane & 15, g = lane >> 4;
#pragma unroll
    for (int m = 0; m < 2; ++m)
#pragma unroll
        for (int n = 0; n < 4; ++n) acc[m][n] = 0.0f;
#pragma unroll
    for (int s = 0; s < KS; ++s) {
        bf16x8 aA = *reinterpret_cast<const bf16x8*>(src + c16 * P + kofs + s * 32 + g * 8);
        bf16x8 aB = *reinterpret_cast<const bf16x8*>(src + (16 + c16) * P + kofs + s * 32 + g * 8);
#pragma unroll
        for (int n = 0; n < 4; ++n) {
            bf16x8 bb = wfrag(W, s, n, lane);
            acc[0][n] = mfma16(aA, bb, acc[0][n]);
            acc[1][n] = mfma16(aB, bb, acc[1][n]);
        }
    }
}

template<int P, int KS>
__device__ __forceinline__ void mm1s(const bf16* __restrict__ src, int kofs,
                                     const bf16* __restrict__ W,
                                     int lane, f32x4 (&acc)[4]) {
    const int c16 = lane & 15, g = lane >> 4;
#pragma unroll
    for (int n = 0; n < 4; ++n) acc[n] = 0.0f;
#pragma unroll
    for (int s = 0; s < KS; ++s) {
        bf16x8 a = *reinterpret_cast<const bf16x8*>(src + c16 * P + kofs + s * 32 + g * 8);
#pragma unroll
        for (int n = 0; n < 4; ++n) {
            bf16x8 bb = wfrag(W, s, n, lane);
            acc[n] = mfma16(a, bb, acc[n]);
        }
    }
}

__device__ __forceinline__ void storeh2(bf16* hbw, const f32x4 (&acc)[2][4],
                                        const float* __restrict__ bias, int c16, int g) {
#pragma unroll
    for (int n = 0; n < 4; ++n) {
        float bb = bias[n * 16 + c16];
#pragma unroll
        for (int m = 0; m < 2; ++m)
#pragma unroll
            for (int r = 0; r < 4; ++r)
                hbw[(m * 16 + g * 4 + r) * 72 + n * 16 + c16] = (bf16)fmaxf(acc[m][n][r] + bb, 0.0f);
    }
}

__device__ __forceinline__ void storeh1(bf16* hbw, const f32x4 (&acc)[4],
                                        const float* __restrict__ bias, int c16, int g) {
#pragma unroll
    for (int n = 0; n < 4; ++n) {
        float bb = bias[n * 16 + c16];
#pragma unroll
        for (int r = 0; r < 4; ++r)
            hbw[(g * 4 + r) * 72 + n * 16 + c16] = (bf16)fmaxf(acc[n][r] + bb, 0.0f);
    }
}

// ---------- prep: f32 -> bf16 weight conversion + fragment-order swizzle ----------
struct PrepArgs {
    const float* src[10];
    bf16* dst[10];
    int ofs[11];
    int ldk[10];
};

__global__ void prep_kernel(PrepArgs a, int totalFrag) {
    int t = blockIdx.x * 256 + threadIdx.x;
    if (t >= totalFrag) return;
    int eb = t * 8;
    int k = 0;
    while (k < 9 && eb >= a.ofs[k + 1]) ++k;
    int f = (eb - a.ofs[k]) >> 3;
    int lane = f & 63, n = (f >> 6) & 3, s = f >> 8;
    int c16 = lane & 15, g = lane >> 4;
    const float* sp = a.src[k] + (n * 16 + c16) * a.ldk[k] + s * 32 + g * 8;
    float4 v0 = *reinterpret_cast<const float4*>(sp);
    float4 v1 = *reinterpret_cast<const float4*>(sp + 4);
    stash8(a.dst[k] + (size_t)f * 8, v0, v1);
}

// ---------- xb: x f32 -> bf16 copy (halves gather bytes, L3-resident) ----------
__global__ __launch_bounds__(256) void xb_kernel(const float* __restrict__ x,
                                                 bf16* __restrict__ xb, int total8) {
    int t = blockIdx.x * 256 + threadIdx.x;
    if (t >= total8) return;
    const float4* p = reinterpret_cast<const float4*>(x) + t * 2;
    stash8(xb + (size_t)t * 8, p[0], p[1]);
}

// ---------- degree count ----------
__global__ __launch_bounds__(256) void degcnt_kernel(const int* __restrict__ ei,
                                                     int* __restrict__ deg, int E) {
    int e = blockIdx.x * 256 + threadIdx.x;
    if (e < E) atomicAdd(&deg[ei[E + e]], 1);
}

// ---------- CSR scan ----------
__global__ __launch_bounds__(256) void scan1_kernel(const int* __restrict__ deg, int* __restrict__ ofs,
                                                    int* __restrict__ bsum, int N) {
    __shared__ int ws4[4];
    const int t = threadIdx.x, lane = t & 63, w = t >> 6;
    const int i = blockIdx.x * 256 + t;
    const int v = (i < N) ? deg[i] : 0;
    int inc = v;
#pragma unroll
    for (int o = 1; o < 64; o <<= 1) { int u = __shfl_up(inc, o); if (lane >= o) inc += u; }
    if (lane == 63) ws4[w] = inc;
    __syncthreads();
    int add = 0;
    for (int k = 0; k < w; ++k) add += ws4[k];
    if (i < N) ofs[i] = inc - v + add;
    if (t == 255) bsum[blockIdx.x] = inc + add;
}

__global__ __launch_bounds__(256) void scan2_kernel(int* __restrict__ bsum, int nb) {
    __shared__ int ws4[4];
    const int t = threadIdx.x, lane = t & 63, w = t >> 6;
    const int v = (t < nb) ? bsum[t] : 0;
    int inc = v;
#pragma unroll
    for (int o = 1; o < 64; o <<= 1) { int u = __shfl_up(inc, o); if (lane >= o) inc += u; }
    if (lane == 63) ws4[w] = inc;
    __syncthreads();
    int add = 0;
    for (int k = 0; k < w; ++k) add += ws4[k];
    if (t < nb) bsum[t] = inc - v + add;
}

__global__ __launch_bounds__(256) void scan3_kernel(int* __restrict__ ofs, const int* __restrict__ bsum, int N) {
    const int i = blockIdx.x * 256 + threadIdx.x;
    if (i < N) ofs[i] += bsum[blockIdx.x];
}

// ---------- CSR fill: position p holds original edge id + its dst ----------
__global__ __launch_bounds__(256) void fill_kernel(const int* __restrict__ ei, const int* __restrict__ ofs,
                                                   int* __restrict__ cur, int* __restrict__ eidT,
                                                   int* __restrict__ dstC, int E) {
    const int e = blockIdx.x * 256 + threadIdx.x;
    if (e >= E) return;
    const int d = ei[E + e];
    const int slot = atomicAdd(&cur[d], 1);
    const int p = ofs[d] + slot;
    eidT[p] = e;
    dstC[p] = d;
}

// ---------- E1 (CSR order): edge MLP + QKV + scores ----------
// 4 waves/block, 32 CSR positions/wave. dst-sorted order -> x_dst gathers are
// L1-broadcast hits; scores/V stored dense at CSR position.
__global__ __launch_bounds__(256, 4) void e1_kernel(
    const bf16* __restrict__ xb, const int* __restrict__ ei, const float* __restrict__ ea,
    const int* __restrict__ eidT, const int* __restrict__ dstC,
    const bf16* __restrict__ W0, const bf16* __restrict__ W1, const bf16* __restrict__ W2,
    const bf16* __restrict__ Wq, const bf16* __restrict__ Wk, const bf16* __restrict__ Wv,
    const float* __restrict__ b0, const float* __restrict__ b1, const float* __restrict__ b2,
    const float* __restrict__ egm, const float* __restrict__ ebe,
    float* __restrict__ scoresOut, bf16* __restrict__ Vout, float* __restrict__ eout, int E)
{
    __shared__ bf16 eas[4][32][72];   // edge_attr rows (bf16), pitch 72
    __shared__ bf16 hbl[4][32][72];   // inter-layer transpose buffer, pitch 72
    const int w = threadIdx.x >> 6;
    const int lane = threadIdx.x & 63;
    const int pbase = blockIdx.x * 128 + w * 32;
    bf16* eaw = &eas[w][0][0];
    bf16* hbw = &hbl[w][0][0];
    const int g = lane >> 4, c16 = lane & 15;

    // ---- stage edge_attr rows (gather by original edge id) -> LDS bf16
    {
        const int r = lane >> 1, q = lane & 1;
        const int er = eidT[pbase + r];
        const float4* ep = reinterpret_cast<const float4*>(ea + (size_t)er * 64) + q * 8;
        bf16* row = eaw + r * 72 + q * 32;
#pragma unroll
        for (int j = 0; j < 4; ++j) stash8(row + j * 8, ep[2 * j], ep[2 * j + 1]);
    }

    // ---- direct A-fragment loads of x_dst / x_src (bf16, dst mostly repeated)
    const int eA0 = eidT[pbase + c16], eA1 = eidT[pbase + 16 + c16];
    const int dn0 = dstC[pbase + c16], dn1 = dstC[pbase + 16 + c16];
    const int sn0 = ei[eA0],           sn1 = ei[eA1];
    const bf16* xd0 = xb + (size_t)dn0 * 64;
    const bf16* xd1 = xb + (size_t)dn1 * 64;
    const bf16* xs0 = xb + (size_t)sn0 * 64;
    const bf16* xs1 = xb + (size_t)sn1 * 64;
    bf16x8 fxd[2][2], fxs[2][2];
#pragma unroll
    for (int s = 0; s < 2; ++s) {
        fxd[0][s] = *reinterpret_cast<const bf16x8*>(xd0 + s * 32 + g * 8);
        fxd[1][s] = *reinterpret_cast<const bf16x8*>(xd1 + s * 32 + g * 8);
        fxs[0][s] = *reinterpret_cast<const bf16x8*>(xs0 + s * 32 + g * 8);
        fxs[1][s] = *reinterpret_cast<const bf16x8*>(xs1 + s * 32 + g * 8);
    }

    // ---- Q (x_dst), K (x_src) + per-head scores -> CSR-position dense
    {
        f32x4 aq[2][4], ak[2][4];
#pragma unroll
        for (int m = 0; m < 2; ++m)
#pragma unroll
            for (int n = 0; n < 4; ++n) { aq[m][n] = 0.0f; ak[m][n] = 0.0f; }
#pragma unroll
        for (int s = 0; s < 2; ++s)
#pragma unroll
            for (int n = 0; n < 4; ++n) {
                bf16x8 bq = wfrag(Wq, s, n, lane);
                bf16x8 bk = wfrag(Wk, s, n, lane);
                aq[0][n] = mfma16(fxd[0][s], bq, aq[0][n]);
                aq[1][n] = mfma16(fxd[1][s], bq, aq[1][n]);
                ak[0][n] = mfma16(fxs[0][s], bk, ak[0][n]);
                ak[1][n] = mfma16(fxs[1][s], bk, ak[1][n]);
            }
#pragma unroll
        for (int n = 0; n < 4; ++n) {
#pragma unroll
            for (int m = 0; m < 2; ++m) {
                float pr[4];
#pragma unroll
                for (int r = 0; r < 4; ++r) pr[r] = aq[m][n][r] * ak[m][n][r];
#pragma unroll
                for (int ms = 1; ms < 16; ms <<= 1)
#pragma unroll
                    for (int r = 0; r < 4; ++r) pr[r] += __shfl_xor(pr[r], ms);
                if (c16 == n) {
#pragma unroll
                    for (int r = 0; r < 4; ++r) {
                        int p2 = pbase + m * 16 + g * 4 + r;
                        scoresOut[(size_t)p2 * 4 + n] = pr[r] * 0.25f;  // / sqrt(16)
                    }
                }
            }
        }
    }

    // ---- L0: W0 * [xd | xs | ea]  (K = 192)
    f32x4 acc[2][4], acc2[2][4];
#pragma unroll
    for (int m = 0; m < 2; ++m)
#pragma unroll
        for (int n = 0; n < 4; ++n) acc[m][n] = 0.0f;
#pragma unroll
    for (int s = 0; s < 2; ++s)
#pragma unroll
        for (int n = 0; n < 4; ++n) {
            bf16x8 bd = wfrag(W0, s, n, lane);
            acc[0][n] = mfma16(fxd[0][s], bd, acc[0][n]);
            acc[1][n] = mfma16(fxd[1][s], bd, acc[1][n]);
            bf16x8 bs = wfrag(W0, s + 2, n, lane);
            acc[0][n] = mfma16(fxs[0][s], bs, acc[0][n]);
            acc[1][n] = mfma16(fxs[1][s], bs, acc[1][n]);
        }
#pragma unroll
    for (int s = 0; s < 2; ++s) {
        bf16x8 ae0 = *reinterpret_cast<const bf16x8*>(eaw + c16 * 72 + s * 32 + g * 8);
        bf16x8 ae1 = *reinterpret_cast<const bf16x8*>(eaw + (16 + c16) * 72 + s * 32 + g * 8);
#pragma unroll
        for (int n = 0; n < 4; ++n) {
            bf16x8 be = wfrag(W0, s + 4, n, lane);
            acc[0][n] = mfma16(ae0, be, acc[0][n]);
            acc[1][n] = mfma16(ae1, be, acc[1][n]);
        }
    }

    // ---- relu -> L1 -> relu -> L2 + b2
    storeh2(hbw, acc, b0, c16, g);
    mm2s<72, 2>(hbw, 0, W1, lane, acc);
    storeh2(hbw, acc, b1, c16, g);
    mm2s<72, 2>(hbw, 0, W2, lane, acc2);
#pragma unroll
    for (int n = 0; n < 4; ++n) {
        float bb = b2[n * 16 + c16];
#pragma unroll
        for (int m = 0; m < 2; ++m)
#pragma unroll
            for (int r = 0; r < 4; ++r) acc2[m][n][r] += bb;
    }

    // ---- LayerNorm per edge row
    float mu[2][4], rs[2][4];
#pragma unroll
    for (int m = 0; m < 2; ++m)
#pragma unroll
        for (int r = 0; r < 4; ++r) {
            float s1 = acc2[m][0][r] + acc2[m][1][r] + acc2[m][2][r] + acc2[m][3][r];
            for (int ms = 1; ms < 16; ms <<= 1) s1 += __shfl_xor(s1, ms);
            float mm = s1 * (1.0f / 64.0f);
            float d0 = acc2[m][0][r] - mm, d1 = acc2[m][1][r] - mm;
            float d2 = acc2[m][2][r] - mm, d3 = acc2[m][3][r] - mm;
            float sq = d0 * d0 + d1 * d1 + d2 * d2 + d3 * d3;
            for (int ms = 1; ms < 16; ms <<= 1) sq += __shfl_xor(sq, ms);
            mu[m][r] = mm;
            rs[m][r] = rsqrtf(sq * (1.0f / 64.0f) + 1e-5f);
        }

    // ---- e_new -> hbl (A-layout, bf16)
#pragma unroll
    for (int n = 0; n < 4; ++n) {
        float gg = egm[n * 16 + c16], bb = ebe[n * 16 + c16];
#pragma unroll
        for (int m = 0; m < 2; ++m)
#pragma unroll
            for (int r = 0; r < 4; ++r) {
                int rowi = m * 16 + g * 4 + r;
                float v = (acc2[m][n][r] - mu[m][r]) * rs[m][r] * gg + bb;
                hbw[rowi * 72 + n * 16 + c16] = (bf16)v;
            }
    }

    // ---- eout = edge_attr + e_new (scatter by original id; full 256B rows)
#pragma unroll
    for (int i = 0; i < 8; ++i) {
        int row = i * 4 + (lane >> 4);     // 0..31
        int colf = (lane & 15) * 4;        // 0..60
        const int e = eidT[pbase + row];
        const bf16* hp = hbw + row * 72 + colf;
        const bf16* ap = eaw + row * 72 + colf;
        float4 o;
        o.x = (float)ap[0] + (float)hp[0];
        o.y = (float)ap[1] + (float)hp[1];
        o.z = (float)ap[2] + (float)hp[2];
        o.w = (float)ap[3] + (float)hp[3];
        *reinterpret_cast<float4*>(eout + (size_t)e * 64 + colf) = o;
    }

    // ---- V = e_new @ wv.T ; dense store at CSR position (1KB/instr)
    mm2s<72, 2>(hbw, 0, Wv, lane, acc);
#pragma unroll
    for (int n = 0; n < 4; ++n)
#pragma unroll
        for (int m = 0; m < 2; ++m)
#pragma unroll
            for (int r = 0; r < 4; ++r)
                eaw[(m * 16 + g * 4 + r) * 72 + n * 16 + c16] = (bf16)acc[m][n][r];
#pragma unroll
    for (int k = 0; k < 4; ++k) {
        int row = k * 8 + (lane >> 3);
        int col = (lane & 7) * 8;
        bf16x8 v = *reinterpret_cast<const bf16x8*>(eaw + row * 72 + col);
        *reinterpret_cast<bf16x8*>(Vout + (size_t)(pbase + row) * 64 + col) = v;
    }
}

// ---------- gather: per-node online softmax, SEQUENTIAL scores/V ----------
__global__ __launch_bounds__(256) void gather_kernel(
    const int* __restrict__ deg, const int* __restrict__ ofs,
    const float* __restrict__ scores, const bf16* __restrict__ V,
    bf16* __restrict__ msg, int N)
{
    const int w = threadIdx.x >> 6, lane = threadIdx.x & 63;
    const int n = blockIdx.x * 4 + w;
    if (n >= N) return;
    const int cnt = deg[n];
    const int base = ofs[n];
    const float* sp = scores + (size_t)base * 4;
    const bf16*  vp = V + (size_t)base * 64;
    const int h = lane >> 4;
    float m = -3.4e38f, s = 0.f, acc = 0.f;

    if (cnt > 0) {
        float sc = sp[h];
        float v  = (float)vp[lane];
        for (int i = 1; i <= cnt; ++i) {
            float sc2 = 0.f, v2 = 0.f;
            if (i < cnt) {  // prefetch next (sequential stream)
                sc2 = sp[(size_t)i * 4 + h];
                v2  = (float)vp[(size_t)i * 64 + lane];
            }
            float mn = fmaxf(m, sc);
            float c  = __expf(m - mn);
            float ex = __expf(sc - mn);
            s = s * c + ex;
            acc = acc * c + ex * v;
            m = mn;
            sc = sc2; v = v2;
        }
    }
    msg[(size_t)n * 64 + lane] = (bf16)(acc / (s + 1e-12f));
}

// ---------- N: node MLP ----------
__global__ __launch_bounds__(256, 2) void n_kernel(
    const float* __restrict__ x, const bf16* __restrict__ msg,
    const bf16* __restrict__ Wo, const bf16* __restrict__ W0, const bf16* __restrict__ W1,
    const bf16* __restrict__ W2,
    const float* __restrict__ b0, const float* __restrict__ b1, const float* __restrict__ b2,
    const float* __restrict__ ngm, const float* __restrict__ nbe,
    float* __restrict__ xout, int N)
{
    __shared__ bf16 cat[4][16][136];
    __shared__ bf16 hbl[4][16][72];
    const int w = threadIdx.x >> 6, lane = threadIdx.x & 63;
    const int nbase = blockIdx.x * 64 + w * 16;
    bf16* catw = &cat[w][0][0];
    bf16* hbw  = &hbl[w][0][0];

    {
        const int r = lane >> 2, q = lane & 3;
        const int nd = min(nbase + r, N - 1);
        const float4* xp = reinterpret_cast<const float4*>(x) + (size_t)nd * 16 + q * 4;
        stash8(catw + r * 136 + q * 16,     xp[0], xp[1]);
        stash8(catw + r * 136 + q * 16 + 8, xp[2], xp[3]);
        const bf16* mp = msg + (size_t)nd * 64 + q * 16;
        *reinterpret_cast<bf16x8*>(hbw + r * 72 + q * 16)     = *reinterpret_cast<const bf16x8*>(mp);
        *reinterpret_cast<bf16x8*>(hbw + r * 72 + q * 16 + 8) = *reinterpret_cast<const bf16x8*>(mp + 8);
    }
    const int g = lane >> 4, c16 = lane & 15;
    f32x4 acc[4];

    mm1s<72, 2>(hbw, 0, Wo, lane, acc);
#pragma unroll
    for (int n = 0; n < 4; ++n)
#pragma unroll
        for (int r = 0; r < 4; ++r)
            catw[(g * 4 + r) * 136 + 64 + n * 16 + c16] = (bf16)acc[n][r];

    mm1s<136, 4>(catw, 0, W0, lane, acc);
    storeh1(hbw, acc, b0, c16, g);
    mm1s<72, 2>(hbw, 0, W1, lane, acc);
    storeh1(hbw, acc, b1, c16, g);
    mm1s<72, 2>(hbw, 0, W2, lane, acc);
#pragma unroll
    for (int n = 0; n < 4; ++n) {
        float bb = b2[n * 16 + c16];
#pragma unroll
        for (int r = 0; r < 4; ++r) acc[n][r] += bb;
    }

    float mu[4], rs[4];
#pragma unroll
    for (int r = 0; r < 4; ++r) {
        float s1 = acc[0][r] + acc[1][r] + acc[2][r] + acc[3][r];
        for (int ms = 1; ms < 16; ms <<= 1) s1 += __shfl_xor(s1, ms);
        float mm = s1 * (1.0f / 64.0f);
        float d0 = acc[0][r] - mm, d1 = acc[1][r] - mm, d2 = acc[2][r] - mm, d3 = acc[3][r] - mm;
        float sq = d0 * d0 + d1 * d1 + d2 * d2 + d3 * d3;
        for (int ms = 1; ms < 16; ms <<= 1) sq += __shfl_xor(sq, ms);
        mu[r] = mm;
        rs[r] = rsqrtf(sq * (1.0f / 64.0f) + 1e-5f);
    }
#pragma unroll
    for (int n = 0; n < 4; ++n) {
        float gg = ngm[n * 16 + c16], bb = nbe[n * 16 + c16];
#pragma unroll
        for (int r = 0; r < 4; ++r) {
            int rowi = g * 4 + r;
            int node = nbase + rowi;
            float v = (acc[n][r] - mu[r]) * rs[r] * gg + bb;
            if (node < N) {
                size_t o = (size_t)node * 64 + n * 16 + c16;
                xout[o] = x[o] + v;
            }
        }
    }
}

// ---------- launcher ----------
extern "C" void kernel_launch(void* const* d_in, const int* in_sizes, int n_in,
                              void* d_out, int out_size, void* d_ws, size_t ws_size,
                              hipStream_t stream)
{
    const float* x   = (const float*)d_in[0];
    const int*   ei  = (const int*)d_in[1];
    const float* ea  = (const float*)d_in[2];
    const float* ew0 = (const float*)d_in[3];
    const float* eb0 = (const float*)d_in[4];
    const float* ew1 = (const float*)d_in[5];
    const float* eb1 = (const float*)d_in[6];
    const float* ew2 = (const float*)d_in[7];
    const float* eb2 = (const float*)d_in[8];
    const float* egm = (const float*)d_in[9];
    const float* ebe = (const float*)d_in[10];
    const float* nw0 = (const float*)d_in[11];
    const float* nb0 = (const float*)d_in[12];
    const float* nw1 = (const float*)d_in[13];
    const float* nb1 = (const float*)d_in[14];
    const float* nw2 = (const float*)d_in[15];
    const float* nb2 = (const float*)d_in[16];
    const float* ngm = (const float*)d_in[17];
    const float* nbe = (const float*)d_in[18];
    const float* wq  = (const float*)d_in[19];
    const float* wk  = (const float*)d_in[20];
    const float* wv  = (const float*)d_in[21];
    const float* wo  = (const float*)d_in[22];

    const int Nn = in_sizes[0] / 64;
    const int Ee = in_sizes[1] / 2;

    char* p = (char*)d_ws;
    auto carve = [&](size_t bytes) {
        char* r = p;
        p += (bytes + 255) & ~(size_t)255;
        return r;
    };
    bf16* W0e = (bf16*)carve(64 * 192 * 2);
    bf16* W1e = (bf16*)carve(64 * 64 * 2);
    bf16* W2e = (bf16*)carve(64 * 64 * 2);
    bf16* Wqb = (bf16*)carve(64 * 64 * 2);
    bf16* Wkb = (bf16*)carve(64 * 64 * 2);
    bf16* Wvb = (bf16*)carve(64 * 64 * 2);
    bf16* Wob = (bf16*)carve(64 * 64 * 2);
    bf16* W0n = (bf16*)carve(64 * 128 * 2);
    bf16* W1n = (bf16*)carve(64 * 64 * 2);
    bf16* W2n = (bf16*)carve(64 * 64 * 2);
    float* scores = (float*)carve((size_t)Ee * 4 * 4);
    bf16*  V      = (bf16*)carve((size_t)Ee * 64 * 2);
    bf16*  msg    = (bf16*)carve((size_t)Nn * 64 * 2);
    bf16*  xb     = (bf16*)carve((size_t)Nn * 64 * 2);
    int*   deg    = (int*)carve((size_t)Nn * 4);
    int*   ofs    = (int*)carve((size_t)Nn * 4);
    int*   cur    = (int*)carve((size_t)Nn * 4);
    int*   eidT   = (int*)carve((size_t)Ee * 4);
    int*   dstC   = (int*)carve((size_t)Ee * 4);
    int*   bsum   = (int*)carve(((size_t)Nn / 256 + 2) * 4);

    hipMemsetAsync(deg, 0, (size_t)Nn * 4, stream);
    hipMemsetAsync(cur, 0, (size_t)Nn * 4, stream);

    PrepArgs pa;
    const float* srcs[10] = {ew0, ew1, ew2, wq, wk, wv, wo, nw0, nw1, nw2};
    bf16* dsts[10]        = {W0e, W1e, W2e, Wqb, Wkb, Wvb, Wob, W0n, W1n, W2n};
    const int sizes[10]   = {12288, 4096, 4096, 4096, 4096, 4096, 4096, 8192, 4096, 4096};
    const int ldks[10]    = {192, 64, 64, 64, 64, 64, 64, 128, 64, 64};
    int acc_ofs = 0;
    for (int i = 0; i < 10; ++i) {
        pa.src[i] = srcs[i];
        pa.dst[i] = dsts[i];
        pa.ofs[i] = acc_ofs;
        pa.ldk[i] = ldks[i];
        acc_ofs += sizes[i];
    }
    pa.ofs[10] = acc_ofs;
    const int totalFrag = acc_ofs / 8;
    prep_kernel<<<(totalFrag + 255) / 256, 256, 0, stream>>>(pa, totalFrag);

    const int total8 = Nn * 64 / 8;
    xb_kernel<<<(total8 + 255) / 256, 256, 0, stream>>>(x, xb, total8);

    // CSR build (before e1)
    degcnt_kernel<<<(Ee + 255) / 256, 256, 0, stream>>>(ei, deg, Ee);
    const int nb = (Nn + 255) / 256;
    scan1_kernel<<<nb, 256, 0, stream>>>(deg, ofs, bsum, Nn);
    scan2_kernel<<<1, 256, 0, stream>>>(bsum, nb);
    scan3_kernel<<<nb, 256, 0, stream>>>(ofs, bsum, Nn);
    fill_kernel<<<(Ee + 255) / 256, 256, 0, stream>>>(ei, ofs, cur, eidT, dstC, Ee);

    float* xout = (float*)d_out;
    float* eout = (float*)d_out + (size_t)Nn * 64;

    // edge MLP + scores + V (CSR order)
    e1_kernel<<<Ee / 128, 256, 0, stream>>>(xb, ei, ea, eidT, dstC,
                                            W0e, W1e, W2e, Wqb, Wkb, Wvb,
                                            eb0, eb1, eb2, egm, ebe,
                                            scores, V, eout, Ee);

    // per-node softmax-weighted gather (sequential streams)
    gather_kernel<<<(Nn + 3) / 4, 256, 0, stream>>>(deg, ofs, scores, V, msg, Nn);

    // node MLP
    n_kernel<<<(Nn + 63) / 64, 256, 0, stream>>>(x, msg, Wob, W0n, W1n, W2n,
                                                 nb0, nb1, nb2, ngm, nbe, xout, Nn);
}

// Round 7
// 466.660 us; speedup vs baseline: 1.2293x; 1.0257x over previous
//
#include <hip/hip_runtime.h>

typedef __bf16 bf16;
typedef __attribute__((ext_vector_type(8))) __bf16 bf16x8;
typedef __attribute__((ext_vector_type(4))) __bf16 bf16x4;
typedef __attribute__((ext_vector_type(4))) float  f32x4;

// ---------- helpers ----------
__device__ __forceinline__ f32x4 mfma16(bf16x8 a, bf16x8 b, f32x4 c) {
    return __builtin_amdgcn_mfma_f32_16x16x32_bf16(a, b, c, 0, 0, 0);
}

__device__ __forceinline__ void stash8(bf16* dst, float4 a, float4 b) {
    bf16x8 v;
    v[0] = (bf16)a.x; v[1] = (bf16)a.y; v[2] = (bf16)a.z; v[3] = (bf16)a.w;
    v[4] = (bf16)b.x; v[5] = (bf16)b.y; v[6] = (bf16)b.z; v[7] = (bf16)b.w;
    *reinterpret_cast<bf16x8*>(dst) = v;
}

// B-fragment from PRE-SWIZZLED weights: 64 lanes read one contiguous 1KB block.
__device__ __forceinline__ bf16x8 wfrag(const bf16* __restrict__ W, int s, int n, int lane) {
    return *reinterpret_cast<const bf16x8*>(W + (((s * 4 + n) * 64 + lane) * 8));
}

// 2-M-tile x 4-N-tile MFMA matmul; A from LDS (pitch P), B swizzled, KS k-steps.
template<int P, int KS>
__device__ __forceinline__ void mm2s(const bf16* __restrict__ src, int kofs,
                                     const bf16* __restrict__ W,
                                     int lane, f32x4 (&acc)[2][4]) {
    const int c16 = lane & 15, g = lane >> 4;
#pragma unroll
    for (int m = 0; m < 2; ++m)
#pragma unroll
        for (int n = 0; n < 4; ++n) acc[m][n] = 0.0f;
#pragma unroll
    for (int s = 0; s < KS; ++s) {
        bf16x8 aA = *reinterpret_cast<const bf16x8*>(src + c16 * P + kofs + s * 32 + g * 8);
        bf16x8 aB = *reinterpret_cast<const bf16x8*>(src + (16 + c16) * P + kofs + s * 32 + g * 8);
#pragma unroll
        for (int n = 0; n < 4; ++n) {
            bf16x8 bb = wfrag(W, s, n, lane);
            acc[0][n] = mfma16(aA, bb, acc[0][n]);
            acc[1][n] = mfma16(aB, bb, acc[1][n]);
        }
    }
}

template<int P, int KS>
__device__ __forceinline__ void mm1s(const bf16* __restrict__ src, int kofs,
                                     const bf16* __restrict__ W,
                                     int lane, f32x4 (&acc)[4]) {
    const int c16 = lane & 15, g = lane >> 4;
#pragma unroll
    for (int n = 0; n < 4; ++n) acc[n] = 0.0f;
#pragma unroll
    for (int s = 0; s < KS; ++s) {
        bf16x8 a = *reinterpret_cast<const bf16x8*>(src + c16 * P + kofs + s * 32 + g * 8);
#pragma unroll
        for (int n = 0; n < 4; ++n) {
            bf16x8 bb = wfrag(W, s, n, lane);
            acc[n] = mfma16(a, bb, acc[n]);
        }
    }
}

__device__ __forceinline__ void storeh2(bf16* hbw, const f32x4 (&acc)[2][4],
                                        const float* __restrict__ bias, int c16, int g) {
#pragma unroll
    for (int n = 0; n < 4; ++n) {
        float bb = bias[n * 16 + c16];
#pragma unroll
        for (int m = 0; m < 2; ++m)
#pragma unroll
            for (int r = 0; r < 4; ++r)
                hbw[(m * 16 + g * 4 + r) * 72 + n * 16 + c16] = (bf16)fmaxf(acc[m][n][r] + bb, 0.0f);
    }
}

__device__ __forceinline__ void storeh1(bf16* hbw, const f32x4 (&acc)[4],
                                        const float* __restrict__ bias, int c16, int g) {
#pragma unroll
    for (int n = 0; n < 4; ++n) {
        float bb = bias[n * 16 + c16];
#pragma unroll
        for (int r = 0; r < 4; ++r)
            hbw[(g * 4 + r) * 72 + n * 16 + c16] = (bf16)fmaxf(acc[n][r] + bb, 0.0f);
    }
}

// ---------- prep: f32 -> bf16 weight conversion + fragment-order swizzle ----------
struct PrepArgs {
    const float* src[10];
    bf16* dst[10];
    int ofs[11];
    int ldk[10];
};

__global__ void prep_kernel(PrepArgs a, int totalFrag) {
    int t = blockIdx.x * 256 + threadIdx.x;
    if (t >= totalFrag) return;
    int eb = t * 8;
    int k = 0;
    while (k < 9 && eb >= a.ofs[k + 1]) ++k;
    int f = (eb - a.ofs[k]) >> 3;
    int lane = f & 63, n = (f >> 6) & 3, s = f >> 8;
    int c16 = lane & 15, g = lane >> 4;
    const float* sp = a.src[k] + (n * 16 + c16) * a.ldk[k] + s * 32 + g * 8;
    float4 v0 = *reinterpret_cast<const float4*>(sp);
    float4 v1 = *reinterpret_cast<const float4*>(sp + 4);
    stash8(a.dst[k] + (size_t)f * 8, v0, v1);
}

// ---------- xb: x f32 -> bf16 copy (halves gather bytes, L3-resident) ----------
__global__ __launch_bounds__(256) void xb_kernel(const float* __restrict__ x,
                                                 bf16* __restrict__ xb, int total8) {
    int t = blockIdx.x * 256 + threadIdx.x;
    if (t >= total8) return;
    const float4* p = reinterpret_cast<const float4*>(x) + t * 2;
    stash8(xb + (size_t)t * 8, p[0], p[1]);
}

// ---------- degree count ----------
__global__ __launch_bounds__(256) void degcnt_kernel(const int* __restrict__ ei,
                                                     int* __restrict__ deg, int E) {
    int e = blockIdx.x * 256 + threadIdx.x;
    if (e < E) atomicAdd(&deg[ei[E + e]], 1);
}

// ---------- CSR scan ----------
__global__ __launch_bounds__(256) void scan1_kernel(const int* __restrict__ deg, int* __restrict__ ofs,
                                                    int* __restrict__ bsum, int N) {
    __shared__ int ws4[4];
    const int t = threadIdx.x, lane = t & 63, w = t >> 6;
    const int i = blockIdx.x * 256 + t;
    const int v = (i < N) ? deg[i] : 0;
    int inc = v;
#pragma unroll
    for (int o = 1; o < 64; o <<= 1) { int u = __shfl_up(inc, o); if (lane >= o) inc += u; }
    if (lane == 63) ws4[w] = inc;
    __syncthreads();
    int add = 0;
    for (int k = 0; k < w; ++k) add += ws4[k];
    if (i < N) ofs[i] = inc - v + add;
    if (t == 255) bsum[blockIdx.x] = inc + add;
}

__global__ __launch_bounds__(256) void scan2_kernel(int* __restrict__ bsum, int nb) {
    __shared__ int ws4[4];
    const int t = threadIdx.x, lane = t & 63, w = t >> 6;
    const int v = (t < nb) ? bsum[t] : 0;
    int inc = v;
#pragma unroll
    for (int o = 1; o < 64; o <<= 1) { int u = __shfl_up(inc, o); if (lane >= o) inc += u; }
    if (lane == 63) ws4[w] = inc;
    __syncthreads();
    int add = 0;
    for (int k = 0; k < w; ++k) add += ws4[k];
    if (t < nb) bsum[t] = inc - v + add;
}

__global__ __launch_bounds__(256) void scan3_kernel(int* __restrict__ ofs, const int* __restrict__ bsum, int N) {
    const int i = blockIdx.x * 256 + threadIdx.x;
    if (i < N) ofs[i] += bsum[blockIdx.x];
}

// ---------- CSR fill: eidT only ----------
__global__ __launch_bounds__(256) void fill_kernel(const int* __restrict__ ei, const int* __restrict__ ofs,
                                                   int* __restrict__ cur, int* __restrict__ eidT, int E) {
    const int e = blockIdx.x * 256 + threadIdx.x;
    if (e >= E) return;
    const int d = ei[E + e];
    const int slot = atomicAdd(&cur[d], 1);
    eidT[ofs[d] + slot] = e;
}

// ---------- E1 (ORIGINAL edge order): edge MLP + QKV + scores ----------
// 4 waves/block, 32 edges/wave. All global reads/writes fully sequential
// except xb row-gathers (L3-resident, 6.4 MB). Zero random writes.
__global__ __launch_bounds__(256, 4) void e1_kernel(
    const bf16* __restrict__ xb, const int* __restrict__ ei, const float* __restrict__ ea,
    const bf16* __restrict__ W0, const bf16* __restrict__ W1, const bf16* __restrict__ W2,
    const bf16* __restrict__ Wq, const bf16* __restrict__ Wk, const bf16* __restrict__ Wv,
    const float* __restrict__ b0, const float* __restrict__ b1, const float* __restrict__ b2,
    const float* __restrict__ egm, const float* __restrict__ ebe,
    float* __restrict__ scoresOut, bf16* __restrict__ Vout, float* __restrict__ eout, int E)
{
    __shared__ bf16 eas[4][32][72];   // edge_attr rows (bf16), pitch 72
    __shared__ bf16 hbl[4][32][72];   // inter-layer transpose buffer, pitch 72
    const int w = threadIdx.x >> 6;
    const int lane = threadIdx.x & 63;
    const int ebase = blockIdx.x * 128 + w * 32;
    bf16* eaw = &eas[w][0][0];
    bf16* hbw = &hbl[w][0][0];
    const int g = lane >> 4, c16 = lane & 15;

    // ---- stage edge_attr FLAT (2KB contiguous per iteration) -> LDS bf16
    {
        const float4* eaf = reinterpret_cast<const float4*>(ea + (size_t)ebase * 64);
#pragma unroll
        for (int i = 0; i < 4; ++i) {
            float4 va = eaf[i * 128 + lane * 2];
            float4 vb = eaf[i * 128 + lane * 2 + 1];
            int row = i * 8 + (lane >> 3), col = (lane & 7) * 8;
            stash8(eaw + row * 72 + col, va, vb);
        }
    }

    // ---- direct A-fragment loads of x_dst / x_src from bf16 x (L3-resident)
    const int eA0 = ebase + c16, eA1 = ebase + 16 + c16;
    const int dn0 = ei[E + eA0], dn1 = ei[E + eA1];
    const int sn0 = ei[eA0],     sn1 = ei[eA1];
    const bf16* xd0 = xb + (size_t)dn0 * 64;
    const bf16* xd1 = xb + (size_t)dn1 * 64;
    const bf16* xs0 = xb + (size_t)sn0 * 64;
    const bf16* xs1 = xb + (size_t)sn1 * 64;
    bf16x8 fxd[2][2], fxs[2][2];
#pragma unroll
    for (int s = 0; s < 2; ++s) {
        fxd[0][s] = *reinterpret_cast<const bf16x8*>(xd0 + s * 32 + g * 8);
        fxd[1][s] = *reinterpret_cast<const bf16x8*>(xd1 + s * 32 + g * 8);
        fxs[0][s] = *reinterpret_cast<const bf16x8*>(xs0 + s * 32 + g * 8);
        fxs[1][s] = *reinterpret_cast<const bf16x8*>(xs1 + s * 32 + g * 8);
    }

    // ---- Q (x_dst), K (x_src) + per-head scores -> sequential dense
    {
        f32x4 aq[2][4], ak[2][4];
#pragma unroll
        for (int m = 0; m < 2; ++m)
#pragma unroll
            for (int n = 0; n < 4; ++n) { aq[m][n] = 0.0f; ak[m][n] = 0.0f; }
#pragma unroll
        for (int s = 0; s < 2; ++s)
#pragma unroll
            for (int n = 0; n < 4; ++n) {
                bf16x8 bq = wfrag(Wq, s, n, lane);
                bf16x8 bk = wfrag(Wk, s, n, lane);
                aq[0][n] = mfma16(fxd[0][s], bq, aq[0][n]);
                aq[1][n] = mfma16(fxd[1][s], bq, aq[1][n]);
                ak[0][n] = mfma16(fxs[0][s], bk, ak[0][n]);
                ak[1][n] = mfma16(fxs[1][s], bk, ak[1][n]);
            }
#pragma unroll
        for (int n = 0; n < 4; ++n) {
#pragma unroll
            for (int m = 0; m < 2; ++m) {
                float pr[4];
#pragma unroll
                for (int r = 0; r < 4; ++r) pr[r] = aq[m][n][r] * ak[m][n][r];
#pragma unroll
                for (int ms = 1; ms < 16; ms <<= 1)
#pragma unroll
                    for (int r = 0; r < 4; ++r) pr[r] += __shfl_xor(pr[r], ms);
                if (c16 == n) {
#pragma unroll
                    for (int r = 0; r < 4; ++r) {
                        int e2 = ebase + m * 16 + g * 4 + r;
                        scoresOut[(size_t)e2 * 4 + n] = pr[r] * 0.25f;  // / sqrt(16)
                    }
                }
            }
        }
    }

    // ---- L0: W0 * [xd | xs | ea]  (K = 192)
    f32x4 acc[2][4], acc2[2][4];
#pragma unroll
    for (int m = 0; m < 2; ++m)
#pragma unroll
        for (int n = 0; n < 4; ++n) acc[m][n] = 0.0f;
#pragma unroll
    for (int s = 0; s < 2; ++s)
#pragma unroll
        for (int n = 0; n < 4; ++n) {
            bf16x8 bd = wfrag(W0, s, n, lane);
            acc[0][n] = mfma16(fxd[0][s], bd, acc[0][n]);
            acc[1][n] = mfma16(fxd[1][s], bd, acc[1][n]);
            bf16x8 bs = wfrag(W0, s + 2, n, lane);
            acc[0][n] = mfma16(fxs[0][s], bs, acc[0][n]);
            acc[1][n] = mfma16(fxs[1][s], bs, acc[1][n]);
        }
#pragma unroll
    for (int s = 0; s < 2; ++s) {
        bf16x8 ae0 = *reinterpret_cast<const bf16x8*>(eaw + c16 * 72 + s * 32 + g * 8);
        bf16x8 ae1 = *reinterpret_cast<const bf16x8*>(eaw + (16 + c16) * 72 + s * 32 + g * 8);
#pragma unroll
        for (int n = 0; n < 4; ++n) {
            bf16x8 be = wfrag(W0, s + 4, n, lane);
            acc[0][n] = mfma16(ae0, be, acc[0][n]);
            acc[1][n] = mfma16(ae1, be, acc[1][n]);
        }
    }

    // ---- relu -> L1 -> relu -> L2 + b2
    storeh2(hbw, acc, b0, c16, g);
    mm2s<72, 2>(hbw, 0, W1, lane, acc);
    storeh2(hbw, acc, b1, c16, g);
    mm2s<72, 2>(hbw, 0, W2, lane, acc2);
#pragma unroll
    for (int n = 0; n < 4; ++n) {
        float bb = b2[n * 16 + c16];
#pragma unroll
        for (int m = 0; m < 2; ++m)
#pragma unroll
            for (int r = 0; r < 4; ++r) acc2[m][n][r] += bb;
    }

    // ---- LayerNorm per edge row
    float mu[2][4], rs[2][4];
#pragma unroll
    for (int m = 0; m < 2; ++m)
#pragma unroll
        for (int r = 0; r < 4; ++r) {
            float s1 = acc2[m][0][r] + acc2[m][1][r] + acc2[m][2][r] + acc2[m][3][r];
            for (int ms = 1; ms < 16; ms <<= 1) s1 += __shfl_xor(s1, ms);
            float mm = s1 * (1.0f / 64.0f);
            float d0 = acc2[m][0][r] - mm, d1 = acc2[m][1][r] - mm;
            float d2 = acc2[m][2][r] - mm, d3 = acc2[m][3][r] - mm;
            float sq = d0 * d0 + d1 * d1 + d2 * d2 + d3 * d3;
            for (int ms = 1; ms < 16; ms <<= 1) sq += __shfl_xor(sq, ms);
            mu[m][r] = mm;
            rs[m][r] = rsqrtf(sq * (1.0f / 64.0f) + 1e-5f);
        }

    // ---- e_new -> hbl (A-layout, bf16)
#pragma unroll
    for (int n = 0; n < 4; ++n) {
        float gg = egm[n * 16 + c16], bb = ebe[n * 16 + c16];
#pragma unroll
        for (int m = 0; m < 2; ++m)
#pragma unroll
            for (int r = 0; r < 4; ++r) {
                int rowi = m * 16 + g * 4 + r;
                float v = (acc2[m][n][r] - mu[m][r]) * rs[m][r] * gg + bb;
                hbw[rowi * 72 + n * 16 + c16] = (bf16)v;
            }
    }

    // ---- eout = edge_attr + e_new, fully sequential f32 (2KB/iter per wave)
#pragma unroll
    for (int i = 0; i < 4; ++i) {
        int row = i * 8 + (lane >> 3), col = (lane & 7) * 8;
        const bf16* hp = hbw + row * 72 + col;
        const bf16* ap = eaw + row * 72 + col;
        float4 o0, o1;
        o0.x = (float)ap[0] + (float)hp[0];
        o0.y = (float)ap[1] + (float)hp[1];
        o0.z = (float)ap[2] + (float)hp[2];
        o0.w = (float)ap[3] + (float)hp[3];
        o1.x = (float)ap[4] + (float)hp[4];
        o1.y = (float)ap[5] + (float)hp[5];
        o1.z = (float)ap[6] + (float)hp[6];
        o1.w = (float)ap[7] + (float)hp[7];
        float4* op = reinterpret_cast<float4*>(eout + (size_t)(ebase + row) * 64 + col);
        op[0] = o0;
        op[1] = o1;
    }

    // ---- V = e_new @ wv.T ; sequential dense store (1KB/instr)
    mm2s<72, 2>(hbw, 0, Wv, lane, acc);
#pragma unroll
    for (int n = 0; n < 4; ++n)
#pragma unroll
        for (int m = 0; m < 2; ++m)
#pragma unroll
            for (int r = 0; r < 4; ++r)
                eaw[(m * 16 + g * 4 + r) * 72 + n * 16 + c16] = (bf16)acc[m][n][r];
#pragma unroll
    for (int k = 0; k < 4; ++k) {
        int row = k * 8 + (lane >> 3);
        int col = (lane & 7) * 8;
        bf16x8 v = *reinterpret_cast<const bf16x8*>(eaw + row * 72 + col);
        *reinterpret_cast<bf16x8*>(Vout + (size_t)(ebase + row) * 64 + col) = v;
    }
}

// ---------- gather: per-node online softmax; V/scores via eidT (random reads, L3) ----------
__global__ __launch_bounds__(256) void gather_kernel(
    const int* __restrict__ deg, const int* __restrict__ ofs, const int* __restrict__ eidT,
    const float* __restrict__ scores, const bf16* __restrict__ V,
    bf16* __restrict__ msg, int N)
{
    const int w = threadIdx.x >> 6, lane = threadIdx.x & 63;
    const int n = blockIdx.x * 4 + w;
    if (n >= N) return;
    const int cnt = deg[n];
    const int* lst = eidT + ofs[n];
    const int h = lane >> 4;
    float m = -3.4e38f, s = 0.f, acc = 0.f;

    // preload up to 128 edge ids into registers (one per lane, two banks)
    int eA = (lane < cnt) ? lst[lane] : 0;
    int eB = (64 + lane < cnt) ? lst[64 + lane] : 0;
    const int nr = min(cnt, 128);
    if (nr > 0) {
        int e = __shfl(eA, 0);
        float sc = scores[(size_t)e * 4 + h];
        float v  = (float)V[(size_t)e * 64 + lane];
        for (int i = 1; i <= nr; ++i) {
            float sc2 = 0.f, v2 = 0.f;
            if (i < nr) {  // prefetch next edge's data while updating with current
                int e2 = __shfl((i < 64) ? eA : eB, i & 63);
                sc2 = scores[(size_t)e2 * 4 + h];
                v2  = (float)V[(size_t)e2 * 64 + lane];
            }
            float mn = fmaxf(m, sc);
            float c  = __expf(m - mn);
            float ex = __expf(sc - mn);
            s = s * c + ex;
            acc = acc * c + ex * v;
            m = mn;
            sc = sc2; v = v2;
        }
    }
    for (int i = 128; i < cnt; ++i) {  // overflow path (deg > 128)
        int e = lst[i];
        float sc = scores[(size_t)e * 4 + h];
        float v  = (float)V[(size_t)e * 64 + lane];
        float mn = fmaxf(m, sc);
        float c  = __expf(m - mn);
        float ex = __expf(sc - mn);
        s = s * c + ex;
        acc = acc * c + ex * v;
        m = mn;
    }
    msg[(size_t)n * 64 + lane] = (bf16)(acc / (s + 1e-12f));
}

// ---------- N: node MLP ----------
__global__ __launch_bounds__(256, 2) void n_kernel(
    const float* __restrict__ x, const bf16* __restrict__ msg,
    const bf16* __restrict__ Wo, const bf16* __restrict__ W0, const bf16* __restrict__ W1,
    const bf16* __restrict__ W2,
    const float* __restrict__ b0, const float* __restrict__ b1, const float* __restrict__ b2,
    const float* __restrict__ ngm, const float* __restrict__ nbe,
    float* __restrict__ xout, int N)
{
    __shared__ bf16 cat[4][16][136];
    __shared__ bf16 hbl[4][16][72];
    const int w = threadIdx.x >> 6, lane = threadIdx.x & 63;
    const int nbase = blockIdx.x * 64 + w * 16;
    bf16* catw = &cat[w][0][0];
    bf16* hbw  = &hbl[w][0][0];

    {
        const int r = lane >> 2, q = lane & 3;
        const int nd = min(nbase + r, N - 1);
        const float4* xp = reinterpret_cast<const float4*>(x) + (size_t)nd * 16 + q * 4;
        stash8(catw + r * 136 + q * 16,     xp[0], xp[1]);
        stash8(catw + r * 136 + q * 16 + 8, xp[2], xp[3]);
        const bf16* mp = msg + (size_t)nd * 64 + q * 16;
        *reinterpret_cast<bf16x8*>(hbw + r * 72 + q * 16)     = *reinterpret_cast<const bf16x8*>(mp);
        *reinterpret_cast<bf16x8*>(hbw + r * 72 + q * 16 + 8) = *reinterpret_cast<const bf16x8*>(mp + 8);
    }
    const int g = lane >> 4, c16 = lane & 15;
    f32x4 acc[4];

    mm1s<72, 2>(hbw, 0, Wo, lane, acc);
#pragma unroll
    for (int n = 0; n < 4; ++n)
#pragma unroll
        for (int r = 0; r < 4; ++r)
            catw[(g * 4 + r) * 136 + 64 + n * 16 + c16] = (bf16)acc[n][r];

    mm1s<136, 4>(catw, 0, W0, lane, acc);
    storeh1(hbw, acc, b0, c16, g);
    mm1s<72, 2>(hbw, 0, W1, lane, acc);
    storeh1(hbw, acc, b1, c16, g);
    mm1s<72, 2>(hbw, 0, W2, lane, acc);
#pragma unroll
    for (int n = 0; n < 4; ++n) {
        float bb = b2[n * 16 + c16];
#pragma unroll
        for (int r = 0; r < 4; ++r) acc[n][r] += bb;
    }

    float mu[4], rs[4];
#pragma unroll
    for (int r = 0; r < 4; ++r) {
        float s1 = acc[0][r] + acc[1][r] + acc[2][r] + acc[3][r];
        for (int ms = 1; ms < 16; ms <<= 1) s1 += __shfl_xor(s1, ms);
        float mm = s1 * (1.0f / 64.0f);
        float d0 = acc[0][r] - mm, d1 = acc[1][r] - mm, d2 = acc[2][r] - mm, d3 = acc[3][r] - mm;
        float sq = d0 * d0 + d1 * d1 + d2 * d2 + d3 * d3;
        for (int ms = 1; ms < 16; ms <<= 1) sq += __shfl_xor(sq, ms);
        mu[r] = mm;
        rs[r] = rsqrtf(sq * (1.0f / 64.0f) + 1e-5f);
    }
#pragma unroll
    for (int n = 0; n < 4; ++n) {
        float gg = ngm[n * 16 + c16], bb = nbe[n * 16 + c16];
#pragma unroll
        for (int r = 0; r < 4; ++r) {
            int rowi = g * 4 + r;
            int node = nbase + rowi;
            float v = (acc[n][r] - mu[r]) * rs[r] * gg + bb;
            if (node < N) {
                size_t o = (size_t)node * 64 + n * 16 + c16;
                xout[o] = x[o] + v;
            }
        }
    }
}

// ---------- launcher ----------
extern "C" void kernel_launch(void* const* d_in, const int* in_sizes, int n_in,
                              void* d_out, int out_size, void* d_ws, size_t ws_size,
                              hipStream_t stream)
{
    const float* x   = (const float*)d_in[0];
    const int*   ei  = (const int*)d_in[1];
    const float* ea  = (const float*)d_in[2];
    const float* ew0 = (const float*)d_in[3];
    const float* eb0 = (const float*)d_in[4];
    const float* ew1 = (const float*)d_in[5];
    const float* eb1 = (const float*)d_in[6];
    const float* ew2 = (const float*)d_in[7];
    const float* eb2 = (const float*)d_in[8];
    const float* egm = (const float*)d_in[9];
    const float* ebe = (const float*)d_in[10];
    const float* nw0 = (const float*)d_in[11];
    const float* nb0 = (const float*)d_in[12];
    const float* nw1 = (const float*)d_in[13];
    const float* nb1 = (const float*)d_in[14];
    const float* nw2 = (const float*)d_in[15];
    const float* nb2 = (const float*)d_in[16];
    const float* ngm = (const float*)d_in[17];
    const float* nbe = (const float*)d_in[18];
    const float* wq  = (const float*)d_in[19];
    const float* wk  = (const float*)d_in[20];
    const float* wv  = (const float*)d_in[21];
    const float* wo  = (const float*)d_in[22];

    const int Nn = in_sizes[0] / 64;
    const int Ee = in_sizes[1] / 2;

    char* p = (char*)d_ws;
    auto carve = [&](size_t bytes) {
        char* r = p;
        p += (bytes + 255) & ~(size_t)255;
        return r;
    };
    bf16* W0e = (bf16*)carve(64 * 192 * 2);
    bf16* W1e = (bf16*)carve(64 * 64 * 2);
    bf16* W2e = (bf16*)carve(64 * 64 * 2);
    bf16* Wqb = (bf16*)carve(64 * 64 * 2);
    bf16* Wkb = (bf16*)carve(64 * 64 * 2);
    bf16* Wvb = (bf16*)carve(64 * 64 * 2);
    bf16* Wob = (bf16*)carve(64 * 64 * 2);
    bf16* W0n = (bf16*)carve(64 * 128 * 2);
    bf16* W1n = (bf16*)carve(64 * 64 * 2);
    bf16* W2n = (bf16*)carve(64 * 64 * 2);
    float* scores = (float*)carve((size_t)Ee * 4 * 4);
    bf16*  V      = (bf16*)carve((size_t)Ee * 64 * 2);
    bf16*  msg    = (bf16*)carve((size_t)Nn * 64 * 2);
    bf16*  xb     = (bf16*)carve((size_t)Nn * 64 * 2);
    int*   deg    = (int*)carve((size_t)Nn * 4);
    int*   ofs    = (int*)carve((size_t)Nn * 4);
    int*   cur    = (int*)carve((size_t)Nn * 4);
    int*   eidT   = (int*)carve((size_t)Ee * 4);
    int*   bsum   = (int*)carve(((size_t)Nn / 256 + 2) * 4);

    hipMemsetAsync(deg, 0, (size_t)Nn * 4, stream);
    hipMemsetAsync(cur, 0, (size_t)Nn * 4, stream);

    PrepArgs pa;
    const float* srcs[10] = {ew0, ew1, ew2, wq, wk, wv, wo, nw0, nw1, nw2};
    bf16* dsts[10]        = {W0e, W1e, W2e, Wqb, Wkb, Wvb, Wob, W0n, W1n, W2n};
    const int sizes[10]   = {12288, 4096, 4096, 4096, 4096, 4096, 4096, 8192, 4096, 4096};
    const int ldks[10]    = {192, 64, 64, 64, 64, 64, 64, 128, 64, 64};
    int acc_ofs = 0;
    for (int i = 0; i < 10; ++i) {
        pa.src[i] = srcs[i];
        pa.dst[i] = dsts[i];
        pa.ofs[i] = acc_ofs;
        pa.ldk[i] = ldks[i];
        acc_ofs += sizes[i];
    }
    pa.ofs[10] = acc_ofs;
    const int totalFrag = acc_ofs / 8;
    prep_kernel<<<(totalFrag + 255) / 256, 256, 0, stream>>>(pa, totalFrag);

    const int total8 = Nn * 64 / 8;
    xb_kernel<<<(total8 + 255) / 256, 256, 0, stream>>>(x, xb, total8);

    // CSR build (for gather)
    degcnt_kernel<<<(Ee + 255) / 256, 256, 0, stream>>>(ei, deg, Ee);
    const int nb = (Nn + 255) / 256;
    scan1_kernel<<<nb, 256, 0, stream>>>(deg, ofs, bsum, Nn);
    scan2_kernel<<<1, 256, 0, stream>>>(bsum, nb);
    scan3_kernel<<<nb, 256, 0, stream>>>(ofs, bsum, Nn);
    fill_kernel<<<(Ee + 255) / 256, 256, 0, stream>>>(ei, ofs, cur, eidT, Ee);

    float* xout = (float*)d_out;
    float* eout = (float*)d_out + (size_t)Nn * 64;

    // edge MLP + scores + V (original order, all-sequential global traffic)
    e1_kernel<<<Ee / 128, 256, 0, stream>>>(xb, ei, ea,
                                            W0e, W1e, W2e, Wqb, Wkb, Wvb,
                                            eb0, eb1, eb2, egm, ebe,
                                            scores, V, eout, Ee);

    // per-node softmax-weighted gather (random reads via eidT, L3-served)
    gather_kernel<<<(Nn + 3) / 4, 256, 0, stream>>>(deg, ofs, eidT, scores, V, msg, Nn);

    // node MLP
    n_kernel<<<(Nn + 63) / 64, 256, 0, stream>>>(x, msg, Wob, W0n, W1n, W2n,
                                                 nb0, nb1, nb2, ngm, nbe, xout, Nn);
}

// Round 8
// 416.156 us; speedup vs baseline: 1.3785x; 1.1214x over previous
//
#include <hip/hip_runtime.h>

typedef __bf16 bf16;
typedef __attribute__((ext_vector_type(8))) __bf16 bf16x8;
typedef __attribute__((ext_vector_type(4))) __bf16 bf16x4;
typedef __attribute__((ext_vector_type(4))) float  f32x4;

// ---------- helpers ----------
__device__ __forceinline__ f32x4 mfma16(bf16x8 a, bf16x8 b, f32x4 c) {
    return __builtin_amdgcn_mfma_f32_16x16x32_bf16(a, b, c, 0, 0, 0);
}

__device__ __forceinline__ void stash8(bf16* dst, float4 a, float4 b) {
    bf16x8 v;
    v[0] = (bf16)a.x; v[1] = (bf16)a.y; v[2] = (bf16)a.z; v[3] = (bf16)a.w;
    v[4] = (bf16)b.x; v[5] = (bf16)b.y; v[6] = (bf16)b.z; v[7] = (bf16)b.w;
    *reinterpret_cast<bf16x8*>(dst) = v;
}

// B-fragment from PRE-SWIZZLED weights: 64 lanes read one contiguous 1KB block.
__device__ __forceinline__ bf16x8 wfrag(const bf16* __restrict__ W, int s, int n, int lane) {
    return *reinterpret_cast<const bf16x8*>(W + (((s * 4 + n) * 64 + lane) * 8));
}

// 2-M-tile x 4-N-tile MFMA matmul; A from LDS (pitch P), B swizzled, KS k-steps.
template<int P, int KS>
__device__ __forceinline__ void mm2s(const bf16* __restrict__ src, int kofs,
                                     const bf16* __restrict__ W,
                                     int lane, f32x4 (&acc)[2][4]) {
    const int c16 = lane & 15, g = lane >> 4;
#pragma unroll
    for (int m = 0; m < 2; ++m)
#pragma unroll
        for (int n = 0; n < 4; ++n) acc[m][n] = 0.0f;
#pragma unroll
    for (int s = 0; s < KS; ++s) {
        bf16x8 aA = *reinterpret_cast<const bf16x8*>(src + c16 * P + kofs + s * 32 + g * 8);
        bf16x8 aB = *reinterpret_cast<const bf16x8*>(src + (16 + c16) * P + kofs + s * 32 + g * 8);
#pragma unroll
        for (int n = 0; n < 4; ++n) {
            bf16x8 bb = wfrag(W, s, n, lane);
            acc[0][n] = mfma16(aA, bb, acc[0][n]);
            acc[1][n] = mfma16(aB, bb, acc[1][n]);
        }
    }
}

template<int P, int KS>
__device__ __forceinline__ void mm1s(const bf16* __restrict__ src, int kofs,
                                     const bf16* __restrict__ W,
                                     int lane, f32x4 (&acc)[4]) {
    const int c16 = lane & 15, g = lane >> 4;
#pragma unroll
    for (int n = 0; n < 4; ++n) acc[n] = 0.0f;
#pragma unroll
    for (int s = 0; s < KS; ++s) {
        bf16x8 a = *reinterpret_cast<const bf16x8*>(src + c16 * P + kofs + s * 32 + g * 8);
#pragma unroll
        for (int n = 0; n < 4; ++n) {
            bf16x8 bb = wfrag(W, s, n, lane);
            acc[n] = mfma16(a, bb, acc[n]);
        }
    }
}

__device__ __forceinline__ void storeh2(bf16* hbw, const f32x4 (&acc)[2][4],
                                        const float* __restrict__ bias, int c16, int g) {
#pragma unroll
    for (int n = 0; n < 4; ++n) {
        float bb = bias[n * 16 + c16];
#pragma unroll
        for (int m = 0; m < 2; ++m)
#pragma unroll
            for (int r = 0; r < 4; ++r)
                hbw[(m * 16 + g * 4 + r) * 72 + n * 16 + c16] = (bf16)fmaxf(acc[m][n][r] + bb, 0.0f);
    }
}

__device__ __forceinline__ void storeh1(bf16* hbw, const f32x4 (&acc)[4],
                                        const float* __restrict__ bias, int c16, int g) {
#pragma unroll
    for (int n = 0; n < 4; ++n) {
        float bb = bias[n * 16 + c16];
#pragma unroll
        for (int r = 0; r < 4; ++r)
            hbw[(g * 4 + r) * 72 + n * 16 + c16] = (bf16)fmaxf(acc[n][r] + bb, 0.0f);
    }
}

// ---------- prep: f32 -> bf16 weight conversion + fragment-order swizzle ----------
struct PrepArgs {
    const float* src[10];
    bf16* dst[10];
    int ofs[11];
    int ldk[10];
};

__global__ void prep_kernel(PrepArgs a, int totalFrag) {
    int t = blockIdx.x * 256 + threadIdx.x;
    if (t >= totalFrag) return;
    int eb = t * 8;
    int k = 0;
    while (k < 9 && eb >= a.ofs[k + 1]) ++k;
    int f = (eb - a.ofs[k]) >> 3;
    int lane = f & 63, n = (f >> 6) & 3, s = f >> 8;
    int c16 = lane & 15, g = lane >> 4;
    const float* sp = a.src[k] + (n * 16 + c16) * a.ldk[k] + s * 32 + g * 8;
    float4 v0 = *reinterpret_cast<const float4*>(sp);
    float4 v1 = *reinterpret_cast<const float4*>(sp + 4);
    stash8(a.dst[k] + (size_t)f * 8, v0, v1);
}

// ---------- xb: x f32 -> bf16 copy (halves gather bytes, L3-resident) ----------
__global__ __launch_bounds__(256) void xb_kernel(const float* __restrict__ x,
                                                 bf16* __restrict__ xb, int total8) {
    int t = blockIdx.x * 256 + threadIdx.x;
    if (t >= total8) return;
    const float4* p = reinterpret_cast<const float4*>(x) + t * 2;
    stash8(xb + (size_t)t * 8, p[0], p[1]);
}

// ---------- degree count ----------
__global__ __launch_bounds__(256) void degcnt_kernel(const int* __restrict__ ei,
                                                     int* __restrict__ deg, int E) {
    int e = blockIdx.x * 256 + threadIdx.x;
    if (e < E) atomicAdd(&deg[ei[E + e]], 1);
}

// ---------- CSR scan ----------
__global__ __launch_bounds__(256) void scan1_kernel(const int* __restrict__ deg, int* __restrict__ ofs,
                                                    int* __restrict__ bsum, int N) {
    __shared__ int ws4[4];
    const int t = threadIdx.x, lane = t & 63, w = t >> 6;
    const int i = blockIdx.x * 256 + t;
    const int v = (i < N) ? deg[i] : 0;
    int inc = v;
#pragma unroll
    for (int o = 1; o < 64; o <<= 1) { int u = __shfl_up(inc, o); if (lane >= o) inc += u; }
    if (lane == 63) ws4[w] = inc;
    __syncthreads();
    int add = 0;
    for (int k = 0; k < w; ++k) add += ws4[k];
    if (i < N) ofs[i] = inc - v + add;
    if (t == 255) bsum[blockIdx.x] = inc + add;
}

__global__ __launch_bounds__(256) void scan2_kernel(int* __restrict__ bsum, int nb) {
    __shared__ int ws4[4];
    const int t = threadIdx.x, lane = t & 63, w = t >> 6;
    const int v = (t < nb) ? bsum[t] : 0;
    int inc = v;
#pragma unroll
    for (int o = 1; o < 64; o <<= 1) { int u = __shfl_up(inc, o); if (lane >= o) inc += u; }
    if (lane == 63) ws4[w] = inc;
    __syncthreads();
    int add = 0;
    for (int k = 0; k < w; ++k) add += ws4[k];
    if (t < nb) bsum[t] = inc - v + add;
}

__global__ __launch_bounds__(256) void scan3_kernel(int* __restrict__ ofs, const int* __restrict__ bsum, int N) {
    const int i = blockIdx.x * 256 + threadIdx.x;
    if (i < N) ofs[i] += bsum[blockIdx.x];
}

// ---------- CSR fill: eidT only ----------
__global__ __launch_bounds__(256) void fill_kernel(const int* __restrict__ ei, const int* __restrict__ ofs,
                                                   int* __restrict__ cur, int* __restrict__ eidT, int E) {
    const int e = blockIdx.x * 256 + threadIdx.x;
    if (e >= E) return;
    const int d = ei[E + e];
    const int slot = atomicAdd(&cur[d], 1);
    eidT[ofs[d] + slot] = e;
}

// ---------- E1 (ORIGINAL edge order): edge MLP + QKV + scores ----------
// All global access instructions are LANE-CONTIGUOUS (lane i covers bytes
// i*W..i*W+W-1 of one block): ea reads 1KB/instr, eout stores 1KB/instr,
// V stores 1KB/instr, scores stores 512B/instr (LDS-staged).
__global__ __launch_bounds__(256, 4) void e1_kernel(
    const bf16* __restrict__ xb, const int* __restrict__ ei, const float* __restrict__ ea,
    const bf16* __restrict__ W0, const bf16* __restrict__ W1, const bf16* __restrict__ W2,
    const bf16* __restrict__ Wq, const bf16* __restrict__ Wk, const bf16* __restrict__ Wv,
    const float* __restrict__ b0, const float* __restrict__ b1, const float* __restrict__ b2,
    const float* __restrict__ egm, const float* __restrict__ ebe,
    float* __restrict__ scoresOut, bf16* __restrict__ Vout, float* __restrict__ eout, int E)
{
    __shared__ bf16 eas[4][32][72];   // edge_attr rows (bf16), pitch 72
    __shared__ bf16 hbl[4][32][72];   // inter-layer transpose buffer, pitch 72
    const int w = threadIdx.x >> 6;
    const int lane = threadIdx.x & 63;
    const int ebase = blockIdx.x * 128 + w * 32;
    bf16* eaw = &eas[w][0][0];
    bf16* hbw = &hbl[w][0][0];
    const int g = lane >> 4, c16 = lane & 15;

    // ---- stage edge_attr -> LDS bf16; each read instruction = 1KB contiguous
    {
        const int rr = lane >> 4;          // 0..3
        const int cc = (lane & 15) * 4;    // 0..60
#pragma unroll
        for (int i = 0; i < 8; ++i) {
            int row = i * 4 + rr;
            float4 v = *reinterpret_cast<const float4*>(ea + (size_t)(ebase + row) * 64 + cc);
            bf16x4 o;
            o[0] = (bf16)v.x; o[1] = (bf16)v.y; o[2] = (bf16)v.z; o[3] = (bf16)v.w;
            *reinterpret_cast<bf16x4*>(eaw + row * 72 + cc) = o;
        }
    }

    // ---- direct A-fragment loads of x_dst / x_src from bf16 x (L3-resident)
    const int eA0 = ebase + c16, eA1 = ebase + 16 + c16;
    const int dn0 = ei[E + eA0], dn1 = ei[E + eA1];
    const int sn0 = ei[eA0],     sn1 = ei[eA1];
    const bf16* xd0 = xb + (size_t)dn0 * 64;
    const bf16* xd1 = xb + (size_t)dn1 * 64;
    const bf16* xs0 = xb + (size_t)sn0 * 64;
    const bf16* xs1 = xb + (size_t)sn1 * 64;
    bf16x8 fxd[2][2], fxs[2][2];
#pragma unroll
    for (int s = 0; s < 2; ++s) {
        fxd[0][s] = *reinterpret_cast<const bf16x8*>(xd0 + s * 32 + g * 8);
        fxd[1][s] = *reinterpret_cast<const bf16x8*>(xd1 + s * 32 + g * 8);
        fxs[0][s] = *reinterpret_cast<const bf16x8*>(xs0 + s * 32 + g * 8);
        fxs[1][s] = *reinterpret_cast<const bf16x8*>(xs1 + s * 32 + g * 8);
    }

    // ---- Q (x_dst), K (x_src) + per-head scores; stage in LDS, 512B store
    {
        f32x4 aq[2][4], ak[2][4];
#pragma unroll
        for (int m = 0; m < 2; ++m)
#pragma unroll
            for (int n = 0; n < 4; ++n) { aq[m][n] = 0.0f; ak[m][n] = 0.0f; }
#pragma unroll
        for (int s = 0; s < 2; ++s)
#pragma unroll
            for (int n = 0; n < 4; ++n) {
                bf16x8 bq = wfrag(Wq, s, n, lane);
                bf16x8 bk = wfrag(Wk, s, n, lane);
                aq[0][n] = mfma16(fxd[0][s], bq, aq[0][n]);
                aq[1][n] = mfma16(fxd[1][s], bq, aq[1][n]);
                ak[0][n] = mfma16(fxs[0][s], bk, ak[0][n]);
                ak[1][n] = mfma16(fxs[1][s], bk, ak[1][n]);
            }
        float* sst = reinterpret_cast<float*>(hbw);  // 512B scratch (pre-L0)
#pragma unroll
        for (int n = 0; n < 4; ++n) {
#pragma unroll
            for (int m = 0; m < 2; ++m) {
                float pr[4];
#pragma unroll
                for (int r = 0; r < 4; ++r) pr[r] = aq[m][n][r] * ak[m][n][r];
#pragma unroll
                for (int ms = 1; ms < 16; ms <<= 1)
#pragma unroll
                    for (int r = 0; r < 4; ++r) pr[r] += __shfl_xor(pr[r], ms);
                if (c16 == n) {
#pragma unroll
                    for (int r = 0; r < 4; ++r)
                        sst[(m * 16 + g * 4 + r) * 4 + n] = pr[r] * 0.25f;  // / sqrt(16)
                }
            }
        }
        // one 64-lane x float2 = 512B contiguous store
        float2 sv = *reinterpret_cast<const float2*>(sst + lane * 2);
        *reinterpret_cast<float2*>(scoresOut + (size_t)ebase * 4 + lane * 2) = sv;
    }

    // ---- L0: W0 * [xd | xs | ea]  (K = 192)
    f32x4 acc[2][4], acc2[2][4];
#pragma unroll
    for (int m = 0; m < 2; ++m)
#pragma unroll
        for (int n = 0; n < 4; ++n) acc[m][n] = 0.0f;
#pragma unroll
    for (int s = 0; s < 2; ++s)
#pragma unroll
        for (int n = 0; n < 4; ++n) {
            bf16x8 bd = wfrag(W0, s, n, lane);
            acc[0][n] = mfma16(fxd[0][s], bd, acc[0][n]);
            acc[1][n] = mfma16(fxd[1][s], bd, acc[1][n]);
            bf16x8 bs = wfrag(W0, s + 2, n, lane);
            acc[0][n] = mfma16(fxs[0][s], bs, acc[0][n]);
            acc[1][n] = mfma16(fxs[1][s], bs, acc[1][n]);
        }
#pragma unroll
    for (int s = 0; s < 2; ++s) {
        bf16x8 ae0 = *reinterpret_cast<const bf16x8*>(eaw + c16 * 72 + s * 32 + g * 8);
        bf16x8 ae1 = *reinterpret_cast<const bf16x8*>(eaw + (16 + c16) * 72 + s * 32 + g * 8);
#pragma unroll
        for (int n = 0; n < 4; ++n) {
            bf16x8 be = wfrag(W0, s + 4, n, lane);
            acc[0][n] = mfma16(ae0, be, acc[0][n]);
            acc[1][n] = mfma16(ae1, be, acc[1][n]);
        }
    }

    // ---- relu -> L1 -> relu -> L2 + b2
    storeh2(hbw, acc, b0, c16, g);
    mm2s<72, 2>(hbw, 0, W1, lane, acc);
    storeh2(hbw, acc, b1, c16, g);
    mm2s<72, 2>(hbw, 0, W2, lane, acc2);
#pragma unroll
    for (int n = 0; n < 4; ++n) {
        float bb = b2[n * 16 + c16];
#pragma unroll
        for (int m = 0; m < 2; ++m)
#pragma unroll
            for (int r = 0; r < 4; ++r) acc2[m][n][r] += bb;
    }

    // ---- LayerNorm per edge row
    float mu[2][4], rs[2][4];
#pragma unroll
    for (int m = 0; m < 2; ++m)
#pragma unroll
        for (int r = 0; r < 4; ++r) {
            float s1 = acc2[m][0][r] + acc2[m][1][r] + acc2[m][2][r] + acc2[m][3][r];
            for (int ms = 1; ms < 16; ms <<= 1) s1 += __shfl_xor(s1, ms);
            float mm = s1 * (1.0f / 64.0f);
            float d0 = acc2[m][0][r] - mm, d1 = acc2[m][1][r] - mm;
            float d2 = acc2[m][2][r] - mm, d3 = acc2[m][3][r] - mm;
            float sq = d0 * d0 + d1 * d1 + d2 * d2 + d3 * d3;
            for (int ms = 1; ms < 16; ms <<= 1) sq += __shfl_xor(sq, ms);
            mu[m][r] = mm;
            rs[m][r] = rsqrtf(sq * (1.0f / 64.0f) + 1e-5f);
        }

    // ---- e_new -> hbl (A-layout, bf16)
#pragma unroll
    for (int n = 0; n < 4; ++n) {
        float gg = egm[n * 16 + c16], bb = ebe[n * 16 + c16];
#pragma unroll
        for (int m = 0; m < 2; ++m)
#pragma unroll
            for (int r = 0; r < 4; ++r) {
                int rowi = m * 16 + g * 4 + r;
                float v = (acc2[m][n][r] - mu[m][r]) * rs[m][r] * gg + bb;
                hbw[rowi * 72 + n * 16 + c16] = (bf16)v;
            }
    }

    // ---- eout = edge_attr + e_new; each store instruction = 1KB contiguous
    {
        const int rr = lane >> 4;          // 0..3
        const int cc = (lane & 15) * 4;    // 0..60
#pragma unroll
        for (int i = 0; i < 8; ++i) {
            int row = i * 4 + rr;
            bf16x4 hv = *reinterpret_cast<const bf16x4*>(hbw + row * 72 + cc);
            bf16x4 av = *reinterpret_cast<const bf16x4*>(eaw + row * 72 + cc);
            float4 o;
            o.x = (float)av[0] + (float)hv[0];
            o.y = (float)av[1] + (float)hv[1];
            o.z = (float)av[2] + (float)hv[2];
            o.w = (float)av[3] + (float)hv[3];
            *reinterpret_cast<float4*>(eout + (size_t)(ebase + row) * 64 + cc) = o;
        }
    }

    // ---- V = e_new @ wv.T ; 1KB-contiguous stores
    mm2s<72, 2>(hbw, 0, Wv, lane, acc);
#pragma unroll
    for (int n = 0; n < 4; ++n)
#pragma unroll
        for (int m = 0; m < 2; ++m)
#pragma unroll
            for (int r = 0; r < 4; ++r)
                eaw[(m * 16 + g * 4 + r) * 72 + n * 16 + c16] = (bf16)acc[m][n][r];
#pragma unroll
    for (int k = 0; k < 4; ++k) {
        int row = k * 8 + (lane >> 3);
        int col = (lane & 7) * 8;
        bf16x8 v = *reinterpret_cast<const bf16x8*>(eaw + row * 72 + col);
        *reinterpret_cast<bf16x8*>(Vout + (size_t)(ebase + row) * 64 + col) = v;
    }
}

// ---------- gather: per-node online softmax; V/scores via eidT (random reads, L3) ----------
__global__ __launch_bounds__(256) void gather_kernel(
    const int* __restrict__ deg, const int* __restrict__ ofs, const int* __restrict__ eidT,
    const float* __restrict__ scores, const bf16* __restrict__ V,
    bf16* __restrict__ msg, int N)
{
    const int w = threadIdx.x >> 6, lane = threadIdx.x & 63;
    const int n = blockIdx.x * 4 + w;
    if (n >= N) return;
    const int cnt = deg[n];
    const int* lst = eidT + ofs[n];
    const int h = lane >> 4;
    float m = -3.4e38f, s = 0.f, acc = 0.f;

    int eA = (lane < cnt) ? lst[lane] : 0;
    int eB = (64 + lane < cnt) ? lst[64 + lane] : 0;
    const int nr = min(cnt, 128);
    if (nr > 0) {
        int e = __shfl(eA, 0);
        float sc = scores[(size_t)e * 4 + h];
        float v  = (float)V[(size_t)e * 64 + lane];
        for (int i = 1; i <= nr; ++i) {
            float sc2 = 0.f, v2 = 0.f;
            if (i < nr) {
                int e2 = __shfl((i < 64) ? eA : eB, i & 63);
                sc2 = scores[(size_t)e2 * 4 + h];
                v2  = (float)V[(size_t)e2 * 64 + lane];
            }
            float mn = fmaxf(m, sc);
            float c  = __expf(m - mn);
            float ex = __expf(sc - mn);
            s = s * c + ex;
            acc = acc * c + ex * v;
            m = mn;
            sc = sc2; v = v2;
        }
    }
    for (int i = 128; i < cnt; ++i) {
        int e = lst[i];
        float sc = scores[(size_t)e * 4 + h];
        float v  = (float)V[(size_t)e * 64 + lane];
        float mn = fmaxf(m, sc);
        float c  = __expf(m - mn);
        float ex = __expf(sc - mn);
        s = s * c + ex;
        acc = acc * c + ex * v;
        m = mn;
    }
    msg[(size_t)n * 64 + lane] = (bf16)(acc / (s + 1e-12f));
}

// ---------- N: node MLP ----------
__global__ __launch_bounds__(256, 4) void n_kernel(
    const float* __restrict__ x, const bf16* __restrict__ msg,
    const bf16* __restrict__ Wo, const bf16* __restrict__ W0, const bf16* __restrict__ W1,
    const bf16* __restrict__ W2,
    const float* __restrict__ b0, const float* __restrict__ b1, const float* __restrict__ b2,
    const float* __restrict__ ngm, const float* __restrict__ nbe,
    float* __restrict__ xout, int N)
{
    __shared__ bf16 cat[4][16][136];
    __shared__ bf16 hbl[4][16][72];
    const int w = threadIdx.x >> 6, lane = threadIdx.x & 63;
    const int nbase = blockIdx.x * 64 + w * 16;
    bf16* catw = &cat[w][0][0];
    bf16* hbw  = &hbl[w][0][0];

    {
        const int r = lane >> 2, q = lane & 3;
        const int nd = min(nbase + r, N - 1);
        const float4* xp = reinterpret_cast<const float4*>(x) + (size_t)nd * 16 + q * 4;
        stash8(catw + r * 136 + q * 16,     xp[0], xp[1]);
        stash8(catw + r * 136 + q * 16 + 8, xp[2], xp[3]);
        const bf16* mp = msg + (size_t)nd * 64 + q * 16;
        *reinterpret_cast<bf16x8*>(hbw + r * 72 + q * 16)     = *reinterpret_cast<const bf16x8*>(mp);
        *reinterpret_cast<bf16x8*>(hbw + r * 72 + q * 16 + 8) = *reinterpret_cast<const bf16x8*>(mp + 8);
    }
    const int g = lane >> 4, c16 = lane & 15;
    f32x4 acc[4];

    mm1s<72, 2>(hbw, 0, Wo, lane, acc);
#pragma unroll
    for (int n = 0; n < 4; ++n)
#pragma unroll
        for (int r = 0; r < 4; ++r)
            catw[(g * 4 + r) * 136 + 64 + n * 16 + c16] = (bf16)acc[n][r];

    mm1s<136, 4>(catw, 0, W0, lane, acc);
    storeh1(hbw, acc, b0, c16, g);
    mm1s<72, 2>(hbw, 0, W1, lane, acc);
    storeh1(hbw, acc, b1, c16, g);
    mm1s<72, 2>(hbw, 0, W2, lane, acc);
#pragma unroll
    for (int n = 0; n < 4; ++n) {
        float bb = b2[n * 16 + c16];
#pragma unroll
        for (int r = 0; r < 4; ++r) acc[n][r] += bb;
    }

    float mu[4], rs[4];
#pragma unroll
    for (int r = 0; r < 4; ++r) {
        float s1 = acc[0][r] + acc[1][r] + acc[2][r] + acc[3][r];
        for (int ms = 1; ms < 16; ms <<= 1) s1 += __shfl_xor(s1, ms);
        float mm = s1 * (1.0f / 64.0f);
        float d0 = acc[0][r] - mm, d1 = acc[1][r] - mm, d2 = acc[2][r] - mm, d3 = acc[3][r] - mm;
        float sq = d0 * d0 + d1 * d1 + d2 * d2 + d3 * d3;
        for (int ms = 1; ms < 16; ms <<= 1) sq += __shfl_xor(sq, ms);
        mu[r] = mm;
        rs[r] = rsqrtf(sq * (1.0f / 64.0f) + 1e-5f);
    }
#pragma unroll
    for (int n = 0; n < 4; ++n) {
        float gg = ngm[n * 16 + c16], bb = nbe[n * 16 + c16];
#pragma unroll
        for (int r = 0; r < 4; ++r) {
            int rowi = g * 4 + r;
            int node = nbase + rowi;
            float v = (acc[n][r] - mu[r]) * rs[r] * gg + bb;
            if (node < N) {
                size_t o = (size_t)node * 64 + n * 16 + c16;
                xout[o] = x[o] + v;
            }
        }
    }
}

// ---------- launcher ----------
extern "C" void kernel_launch(void* const* d_in, const int* in_sizes, int n_in,
                              void* d_out, int out_size, void* d_ws, size_t ws_size,
                              hipStream_t stream)
{
    const float* x   = (const float*)d_in[0];
    const int*   ei  = (const int*)d_in[1];
    const float* ea  = (const float*)d_in[2];
    const float* ew0 = (const float*)d_in[3];
    const float* eb0 = (const float*)d_in[4];
    const float* ew1 = (const float*)d_in[5];
    const float* eb1 = (const float*)d_in[6];
    const float* ew2 = (const float*)d_in[7];
    const float* eb2 = (const float*)d_in[8];
    const float* egm = (const float*)d_in[9];
    const float* ebe = (const float*)d_in[10];
    const float* nw0 = (const float*)d_in[11];
    const float* nb0 = (const float*)d_in[12];
    const float* nw1 = (const float*)d_in[13];
    const float* nb1 = (const float*)d_in[14];
    const float* nw2 = (const float*)d_in[15];
    const float* nb2 = (const float*)d_in[16];
    const float* ngm = (const float*)d_in[17];
    const float* nbe = (const float*)d_in[18];
    const float* wq  = (const float*)d_in[19];
    const float* wk  = (const float*)d_in[20];
    const float* wv  = (const float*)d_in[21];
    const float* wo  = (const float*)d_in[22];

    const int Nn = in_sizes[0] / 64;
    const int Ee = in_sizes[1] / 2;

    char* p = (char*)d_ws;
    auto carve = [&](size_t bytes) {
        char* r = p;
        p += (bytes + 255) & ~(size_t)255;
        return r;
    };
    bf16* W0e = (bf16*)carve(64 * 192 * 2);
    bf16* W1e = (bf16*)carve(64 * 64 * 2);
    bf16* W2e = (bf16*)carve(64 * 64 * 2);
    bf16* Wqb = (bf16*)carve(64 * 64 * 2);
    bf16* Wkb = (bf16*)carve(64 * 64 * 2);
    bf16* Wvb = (bf16*)carve(64 * 64 * 2);
    bf16* Wob = (bf16*)carve(64 * 64 * 2);
    bf16* W0n = (bf16*)carve(64 * 128 * 2);
    bf16* W1n = (bf16*)carve(64 * 64 * 2);
    bf16* W2n = (bf16*)carve(64 * 64 * 2);
    float* scores = (float*)carve((size_t)Ee * 4 * 4);
    bf16*  V      = (bf16*)carve((size_t)Ee * 64 * 2);
    bf16*  msg    = (bf16*)carve((size_t)Nn * 64 * 2);
    bf16*  xb     = (bf16*)carve((size_t)Nn * 64 * 2);
    int*   deg    = (int*)carve((size_t)Nn * 4);
    int*   ofs    = (int*)carve((size_t)Nn * 4);
    int*   cur    = (int*)carve((size_t)Nn * 4);
    int*   eidT   = (int*)carve((size_t)Ee * 4);
    int*   bsum   = (int*)carve(((size_t)Nn / 256 + 2) * 4);

    hipMemsetAsync(deg, 0, (size_t)Nn * 4, stream);
    hipMemsetAsync(cur, 0, (size_t)Nn * 4, stream);

    PrepArgs pa;
    const float* srcs[10] = {ew0, ew1, ew2, wq, wk, wv, wo, nw0, nw1, nw2};
    bf16* dsts[10]        = {W0e, W1e, W2e, Wqb, Wkb, Wvb, Wob, W0n, W1n, W2n};
    const int sizes[10]   = {12288, 4096, 4096, 4096, 4096, 4096, 4096, 8192, 4096, 4096};
    const int ldks[10]    = {192, 64, 64, 64, 64, 64, 64, 128, 64, 64};
    int acc_ofs = 0;
    for (int i = 0; i < 10; ++i) {
        pa.src[i] = srcs[i];
        pa.dst[i] = dsts[i];
        pa.ofs[i] = acc_ofs;
        pa.ldk[i] = ldks[i];
        acc_ofs += sizes[i];
    }
    pa.ofs[10] = acc_ofs;
    const int totalFrag = acc_ofs / 8;
    prep_kernel<<<(totalFrag + 255) / 256, 256, 0, stream>>>(pa, totalFrag);

    const int total8 = Nn * 64 / 8;
    xb_kernel<<<(total8 + 255) / 256, 256, 0, stream>>>(x, xb, total8);

    // CSR build (for gather)
    degcnt_kernel<<<(Ee + 255) / 256, 256, 0, stream>>>(ei, deg, Ee);
    const int nb = (Nn + 255) / 256;
    scan1_kernel<<<nb, 256, 0, stream>>>(deg, ofs, bsum, Nn);
    scan2_kernel<<<1, 256, 0, stream>>>(bsum, nb);
    scan3_kernel<<<nb, 256, 0, stream>>>(ofs, bsum, Nn);
    fill_kernel<<<(Ee + 255) / 256, 256, 0, stream>>>(ei, ofs, cur, eidT, Ee);

    float* xout = (float*)d_out;
    float* eout = (float*)d_out + (size_t)Nn * 64;

    // edge MLP + scores + V (original order, lane-contiguous global traffic)
    e1_kernel<<<Ee / 128, 256, 0, stream>>>(xb, ei, ea,
                                            W0e, W1e, W2e, Wqb, Wkb, Wvb,
                                            eb0, eb1, eb2, egm, ebe,
                                            scores, V, eout, Ee);

    // per-node softmax-weighted gather (random reads via eidT, L3-served)
    gather_kernel<<<(Nn + 3) / 4, 256, 0, stream>>>(deg, ofs, eidT, scores, V, msg, Nn);

    // node MLP
    n_kernel<<<(Nn + 63) / 64, 256, 0, stream>>>(x, msg, Wob, W0n, W1n, W2n,
                                                 nb0, nb1, nb2, ngm, nbe, xout, Nn);
}